// Round 9
// baseline (3068.988 us; speedup 1.0000x reference)
//
#include <hip/hip_runtime.h>
#include <hip/hip_bf16.h>
#include <math.h>

#define B    128
#define CIN  256
#define HIN  8
#define WIN_ 32
#define RH   16
#define RW   64
#define HID  256
#define NC   163
#define T    32
#define L    256
#define CENC 296

typedef __attribute__((ext_vector_type(8))) short short8;
typedef __attribute__((ext_vector_type(8))) unsigned short u16x8;
typedef __attribute__((ext_vector_type(4))) float f32x4;

__device__ __forceinline__ float bf2f(unsigned short u) {
    unsigned int x = ((unsigned int)u) << 16;
    return __uint_as_float(x);
}
__device__ __forceinline__ unsigned short f2bf(float f) {
    unsigned int x = __float_as_uint(f);
    unsigned int r = (x + 0x7FFFu + ((x >> 16) & 1u)) >> 16;
    return (unsigned short)r;
}
__device__ __forceinline__ float fast_tanh(float x) {
    float e = __expf(2.f * x);
    return 1.f - 2.f * __builtin_amdgcn_rcpf(e + 1.f);
}
__device__ __forceinline__ float fast_sigm(float x) {
    return __builtin_amdgcn_rcpf(1.f + __expf(-x));
}
__device__ __forceinline__ float wave_red_max(float v) {
    #pragma unroll
    for (int o = 32; o > 0; o >>= 1) v = fmaxf(v, __shfl_down(v, o, 64));
    return v;
}
__device__ __forceinline__ float wave_red_sum(float v) {
    #pragma unroll
    for (int o = 32; o > 0; o >>= 1) v += __shfl_down(v, o, 64);
    return v;
}
__device__ __forceinline__ float half_red_sum(float v) {
    #pragma unroll
    for (int o = 16; o > 0; o >>= 1) v += __shfl_down(v, o, 64);
    return v;
}

// ---------------- bilinear upsample fused with transpose → Xt[b][y][x][ci] bf16 ----------------
__global__ void __launch_bounds__(256) k_upsxt(const float* __restrict__ x,
                                               unsigned short* __restrict__ Xt) {
    __shared__ __align__(16) float sf[64 * 2 * 32];
    const int y = blockIdx.x;
    const int b = blockIdx.y;
    const int tid = threadIdx.x;
    float sy = 0.5f * y - 0.25f;
    int yq0 = (y - 1) >> 1;
    float wy = sy - (float)yq0;
    int y0c = min(max(yq0, 0), HIN - 1);
    int y1c = min(max(yq0 + 1, 0), HIN - 1);
    const int xo = tid & 63;
    const int cj = tid >> 6;
    float sx = 0.5f * xo - 0.25f;
    int xq0 = (xo - 1) >> 1;
    float wx = sx - (float)xq0;
    int x0c = min(max(xq0, 0), WIN_ - 1);
    int x1c = min(max(xq0 + 1, 0), WIN_ - 1);
    for (int cc = 0; cc < 4; cc++) {
        __syncthreads();
        #pragma unroll
        for (int i = 0; i < 4; i++) {
            int idx = tid * 4 + i;
            int c = idx >> 4;
            int rowh = (idx >> 3) & 1;
            int part = idx & 7;
            int ysrc = rowh ? y1c : y0c;
            float4 v = *reinterpret_cast<const float4*>(
                x + ((size_t)(b * CIN + cc * 64 + c) * HIN + ysrc) * WIN_ + part * 4);
            *reinterpret_cast<float4*>(sf + ((c * 2 + rowh) * 32 + part * 4)) = v;
        }
        __syncthreads();
        unsigned short ov[16];
        #pragma unroll
        for (int j = 0; j < 16; j++) {
            int c = cj * 16 + j;
            const float* r0 = sf + (c * 2 + 0) * 32;
            const float* r1 = sf + (c * 2 + 1) * 32;
            float v = (1.f - wy) * ((1.f - wx) * r0[x0c] + wx * r0[x1c])
                    +        wy  * ((1.f - wx) * r1[x0c] + wx * r1[x1c]);
            ov[j] = f2bf(v);
        }
        unsigned short* dst = Xt + ((size_t)((b * 16 + y) * 64 + xo)) * 256 + cc * 64 + cj * 16;
        *reinterpret_cast<u16x8*>(dst)     = *reinterpret_cast<u16x8*>(ov);
        *reinterpret_cast<u16x8*>(dst + 8) = *reinterpret_cast<u16x8*>(ov + 8);
    }
}

// ---------------- weight transform: Wt[s][co][ci] bf16 ----------------
__global__ void k_wt(const float* __restrict__ conv_w, unsigned short* __restrict__ Wt) {
    int e = blockIdx.x * 256 + threadIdx.x;
    int ci = e & 255;
    int co = (e >> 8) & 255;
    int s  = e >> 16;
    Wt[(size_t)(s * 256 + co) * 256 + ci] = f2bf(conv_w[(size_t)(co * 256 + ci) * 9 + s]);
}

// ---------------- conv3x3 MFMA implicit GEMM + fused bias/ReLU/pool → enc_bf ----------------
__global__ void __launch_bounds__(256) k_convmm(const unsigned short* __restrict__ Xt,
        const unsigned short* __restrict__ Wt, const float* __restrict__ conv_b,
        unsigned short* __restrict__ enc_bf) {
    __shared__ __align__(16) char smem[34048];
    unsigned short* A_s = (unsigned short*)smem;
    unsigned short* B_s = A_s + 128 * 40;
    float* pool = (float*)smem;
    const int mt = blockIdx.x;
    const int n0 = blockIdx.y * 128;
    const int b = mt >> 3;
    const int y0 = (mt & 7) * 2;
    const int tid = threadIdx.x;
    const int wave = tid >> 6, lane = tid & 63;
    const int mq = (wave & 1) * 64, nq = (wave >> 1) * 64;
    const int lm = lane & 15, lq = lane >> 4;
    f32x4 acc[4][4];
    #pragma unroll
    for (int mi = 0; mi < 4; mi++)
        #pragma unroll
        for (int ni = 0; ni < 4; ni++)
            #pragma unroll
            for (int r = 0; r < 4; r++) acc[mi][ni][r] = 0.f;

    for (int s9 = 0; s9 < 9; s9++) {
        const int ky = s9 / 3, kx = s9 % 3;
        const unsigned short* Wb = Wt + (size_t)s9 * 256 * 256;
        for (int kc = 0; kc < 256; kc += 32) {
            __syncthreads();
            #pragma unroll
            for (int it = 0; it < 2; it++) {
                int s2 = tid + it * 256;
                int pix = s2 >> 2, q4 = s2 & 3;
                int yy = y0 + (pix >> 6) + ky - 1;
                int xx = (pix & 63) + kx - 1;
                u16x8 va = {0, 0, 0, 0, 0, 0, 0, 0};
                if ((unsigned)yy < 16u && (unsigned)xx < 64u)
                    va = *reinterpret_cast<const u16x8*>(
                        Xt + ((size_t)((b * 16 + yy) * 64 + xx)) * 256 + kc + q4 * 8);
                *reinterpret_cast<u16x8*>(A_s + pix * 40 + q4 * 8) = va;
                u16x8 vb = *reinterpret_cast<const u16x8*>(
                    Wb + (size_t)(n0 + pix) * 256 + kc + q4 * 8);
                *reinterpret_cast<u16x8*>(B_s + pix * 40 + q4 * 8) = vb;
            }
            __syncthreads();
            short8 af[4], bfr[4];
            #pragma unroll
            for (int mi = 0; mi < 4; mi++)
                af[mi] = *reinterpret_cast<const short8*>(A_s + (mq + mi * 16 + lm) * 40 + lq * 8);
            #pragma unroll
            for (int ni = 0; ni < 4; ni++)
                bfr[ni] = *reinterpret_cast<const short8*>(B_s + (nq + ni * 16 + lm) * 40 + lq * 8);
            #pragma unroll
            for (int mi = 0; mi < 4; mi++)
                #pragma unroll
                for (int ni = 0; ni < 4; ni++)
                    acc[mi][ni] = __builtin_amdgcn_mfma_f32_16x16x32_bf16(
                        af[mi], bfr[ni], acc[mi][ni], 0, 0, 0);
        }
    }
    __syncthreads();
    #pragma unroll
    for (int mi = 0; mi < 4; mi++) {
        int px0 = mi * 8 + lq * 2;
        #pragma unroll
        for (int ni = 0; ni < 4; ni++) {
            int nl = nq + ni * 16 + lm;
            float pa = fmaxf(acc[mi][ni][0], acc[mi][ni][1]);
            float pb = fmaxf(acc[mi][ni][2], acc[mi][ni][3]);
            pool[((wave & 1) * 32 + px0) * 132 + nl] = pa;
            pool[((wave & 1) * 32 + px0 + 1) * 132 + nl] = pb;
        }
    }
    __syncthreads();
    {
        int base = tid * 16;
        int px = base >> 7;
        int nb = base & 127;
        unsigned short ov[16];
        #pragma unroll
        for (int i = 0; i < 16; i++) {
            int n = nb + i;
            float v = fmaxf(pool[px * 132 + n], pool[(32 + px) * 132 + n]) + conv_b[n0 + n];
            ov[i] = f2bf(fmaxf(v, 0.f));
        }
        unsigned short* dst = enc_bf + ((size_t)b * L + (mt & 7) * 32 + px) * CENC + n0 + nb;
        *reinterpret_cast<u16x8*>(dst)     = *reinterpret_cast<u16x8*>(ov);
        *reinterpret_cast<u16x8*>(dst + 8) = *reinterpret_cast<u16x8*>(ov + 8);
    }
}

// ---------------- positional channels 256..295 (bf16) ----------------
__global__ void k_encpos(const float* __restrict__ x_emb, const float* __restrict__ y_emb,
                         unsigned short* __restrict__ enc_bf) {
    int b = blockIdx.x, l = threadIdx.x;
    int yl = l >> 5, xl = l & 31;
    unsigned short* e = enc_bf + (size_t)(b * L + l) * CENC + 256;
    #pragma unroll
    for (int c = 0; c < 32; c++) e[c] = f2bf(x_emb[xl * 32 + c]);
    #pragma unroll
    for (int c = 0; c < 8; c++) e[32 + c] = f2bf(y_emb[yl * 8 + c]);
}

// ---------------- E[v][h] fp32 ----------------
__global__ void __launch_bounds__(256) k_etab(const float* __restrict__ emb_dec,
                                              const float* __restrict__ word_w,
                                              const float* __restrict__ word_b,
                                              float* __restrict__ E) {
    __shared__ float er[NC];
    int row = blockIdx.x, tid = threadIdx.x;
    for (int k = tid; k < NC; k += 256) er[k] = emb_dec[(size_t)row * NC + k];
    __syncthreads();
    float a = word_b[tid];
    for (int k = 0; k < NC; k++) a += er[k] * word_w[(size_t)tid * NC + k];
    E[(size_t)row * HID + tid] = a;
}

// ---------------- row-major bf16 weight casts ----------------
__global__ void k_prep(const float* __restrict__ attn_w, const float* __restrict__ out_w,
                       unsigned short* __restrict__ wA_bf, unsigned short* __restrict__ ow_bf) {
    int o = blockIdx.x, k = threadIdx.x;
    wA_bf[(size_t)o * 256 + k] = f2bf(attn_w[(size_t)o * 552 + k]);
    if (o < NC) ow_bf[(size_t)o * 256 + k] = f2bf(out_w[(size_t)o * 256 + k]);
}

// ---------------- GRU weight prep ----------------
// Wg1n[g][k] g<768,k<320: wih ctx cols 256..551 (pad 296..319 = 0)
// Wg2T[k][g] k<256: whh transposed (k-major for column-per-thread GEMV)
__global__ void __launch_bounds__(576) k_wg(const float* __restrict__ wih,
                                            const float* __restrict__ whh,
                                            unsigned short* __restrict__ Wg1n,
                                            unsigned short* __restrict__ Wg2T) {
    int g = blockIdx.x, k = threadIdx.x;
    if (k < 320) {
        Wg1n[(size_t)g * 320 + k] = (k < 296) ? f2bf(wih[(size_t)g * 552 + 256 + k]) : 0;
    } else {
        int k2 = k - 320;
        Wg2T[(size_t)k2 * 768 + g] = f2bf(whh[(size_t)g * 256 + k2]);
    }
}
__global__ void __launch_bounds__(768) k_wge(const float* __restrict__ wih,
                                             unsigned short* __restrict__ WgE) {
    int k = blockIdx.x, g = threadIdx.x;
    WgE[(size_t)k * 768 + g] = f2bf(wih[(size_t)g * 552 + k]);
}
// giE[v][g] = emb-part of gi + bih
__global__ void __launch_bounds__(768) k_gie(const float* __restrict__ E,
                                             const unsigned short* __restrict__ WgE,
                                             const float* __restrict__ bih,
                                             float* __restrict__ giE) {
    __shared__ float er[256];
    int v = blockIdx.x, g = threadIdx.x;
    if (g < 256) er[g] = E[(size_t)v * 256 + g];
    __syncthreads();
    float a = bih[g];
    #pragma unroll 4
    for (int k = 0; k < 256; k++) a += er[k] * bf2f(WgE[(size_t)k * 768 + g]);
    giE[(size_t)v * 768 + g] = a;
}

// ---------------- ep_t[b][l][h] bf16 ----------------
__global__ void __launch_bounds__(256) k_ep(const unsigned short* __restrict__ enc_bf,
                                            const float* __restrict__ attn_w,
                                            unsigned short* __restrict__ ep_t) {
    __shared__ __align__(16) float eS[16][132];
    __shared__ __align__(16) float wS[16][36];
    const int l0 = blockIdx.x * 128;
    const int h0 = blockIdx.y * 32;
    const int b = blockIdx.z;
    const int tid = threadIdx.x;
    const int hh = tid >> 5, ll = tid & 31;
    float acc[4][4];
    #pragma unroll
    for (int s2 = 0; s2 < 4; s2++)
        #pragma unroll
        for (int r = 0; r < 4; r++) acc[s2][r] = 0.f;
    for (int kc = 0; kc < CENC; kc += 16) {
        const int kn = min(16, CENC - kc);
        __syncthreads();
        #pragma unroll
        for (int it = 0; it < 2; it++) {
            int idx = it * 256 + tid;
            int lq = idx >> 2, kq = idx & 3;
            float v0 = 0.f, v1 = 0.f, v2 = 0.f, v3 = 0.f;
            if (kq * 4 < kn) {
                ushort4 u = *reinterpret_cast<const ushort4*>(
                    enc_bf + (size_t)(b * L + l0 + lq) * CENC + kc + kq * 4);
                v0 = bf2f(u.x); v1 = bf2f(u.y); v2 = bf2f(u.z); v3 = bf2f(u.w);
            }
            eS[kq * 4 + 0][lq] = v0; eS[kq * 4 + 1][lq] = v1;
            eS[kq * 4 + 2][lq] = v2; eS[kq * 4 + 3][lq] = v3;
        }
        if (tid < 128) {
            int hq = tid >> 2, kq = tid & 3;
            float4 v = make_float4(0.f, 0.f, 0.f, 0.f);
            if (kq * 4 < kn)
                v = *reinterpret_cast<const float4*>(attn_w + (size_t)(h0 + hq) * 552 + 256 + kc + kq * 4);
            wS[kq * 4 + 0][hq] = v.x; wS[kq * 4 + 1][hq] = v.y;
            wS[kq * 4 + 2][hq] = v.z; wS[kq * 4 + 3][hq] = v.w;
        }
        __syncthreads();
        #pragma unroll
        for (int k = 0; k < 16; k++) {
            float4 e = *reinterpret_cast<const float4*>(&eS[k][ll * 4]);
            float4 w = *reinterpret_cast<const float4*>(&wS[k][hh * 4]);
            float ev[4] = {e.x, e.y, e.z, e.w};
            float wv[4] = {w.x, w.y, w.z, w.w};
            #pragma unroll
            for (int s2 = 0; s2 < 4; s2++)
                #pragma unroll
                for (int r = 0; r < 4; r++) acc[s2][r] += wv[s2] * ev[r];
        }
    }
    #pragma unroll
    for (int r = 0; r < 4; r++) {
        ushort4 o;
        o.x = f2bf(acc[0][r]); o.y = f2bf(acc[1][r]);
        o.z = f2bf(acc[2][r]); o.w = f2bf(acc[3][r]);
        *reinterpret_cast<ushort4*>(
            ep_t + ((size_t)(b * L) + l0 + ll * 4 + r) * HID + h0 + hh * 4) = o;
    }
}

// ---------------- geP[b*L+l][g] = Wg1n · enc_bf[b][l]  (MFMA GEMM, M=32768,N=768,K=320) ----------------
// A elements k>=296 read garbage but B (Wg1n) is zero there → product 0. enc_bf has 64B slack.
__global__ void __launch_bounds__(256) k_gep(const unsigned short* __restrict__ enc_bf,
        const unsigned short* __restrict__ Wg1n, unsigned short* __restrict__ geP) {
    __shared__ __align__(16) unsigned short smem[128 * 136];  // A_s/B_s then stage
    unsigned short* A_s = smem;
    unsigned short* B_s = smem + 128 * 40;
    const int mt = blockIdx.x;          // 256 tiles of 128 rows
    const int n0 = blockIdx.y * 128;    // 6 tiles of 128 g
    const int m0 = mt * 128;
    const int tid = threadIdx.x;
    const int wave = tid >> 6, lane = tid & 63;
    const int mq = (wave & 1) * 64, nq = (wave >> 1) * 64;
    const int lm = lane & 15, lq = lane >> 4;
    f32x4 acc[4][4];
    #pragma unroll
    for (int mi = 0; mi < 4; mi++)
        #pragma unroll
        for (int ni = 0; ni < 4; ni++)
            #pragma unroll
            for (int r = 0; r < 4; r++) acc[mi][ni][r] = 0.f;
    for (int kc = 0; kc < 320; kc += 32) {
        __syncthreads();
        #pragma unroll
        for (int it = 0; it < 2; it++) {
            int s2 = tid + it * 256;
            int pix = s2 >> 2, q4 = s2 & 3;
            u16x8 va = *reinterpret_cast<const u16x8*>(
                enc_bf + (size_t)(m0 + pix) * CENC + kc + q4 * 8);
            *reinterpret_cast<u16x8*>(A_s + pix * 40 + q4 * 8) = va;
            u16x8 vb = *reinterpret_cast<const u16x8*>(
                Wg1n + (size_t)(n0 + pix) * 320 + kc + q4 * 8);
            *reinterpret_cast<u16x8*>(B_s + pix * 40 + q4 * 8) = vb;
        }
        __syncthreads();
        short8 af[4], bfr[4];
        #pragma unroll
        for (int mi = 0; mi < 4; mi++)
            af[mi] = *reinterpret_cast<const short8*>(A_s + (mq + mi * 16 + lm) * 40 + lq * 8);
        #pragma unroll
        for (int ni = 0; ni < 4; ni++)
            bfr[ni] = *reinterpret_cast<const short8*>(B_s + (nq + ni * 16 + lm) * 40 + lq * 8);
        #pragma unroll
        for (int mi = 0; mi < 4; mi++)
            #pragma unroll
            for (int ni = 0; ni < 4; ni++)
                acc[mi][ni] = __builtin_amdgcn_mfma_f32_16x16x32_bf16(
                    af[mi], bfr[ni], acc[mi][ni], 0, 0, 0);
    }
    __syncthreads();
    // stage [128 m][136] bf16 then 16B row-major stores
    #pragma unroll
    for (int mi = 0; mi < 4; mi++)
        #pragma unroll
        for (int ni = 0; ni < 4; ni++)
            #pragma unroll
            for (int r = 0; r < 4; r++)
                smem[(mq + mi * 16 + lq * 4 + r) * 136 + nq + ni * 16 + lm] =
                    f2bf(acc[mi][ni][r]);
    __syncthreads();
    {
        int row = tid >> 1, cg = (tid & 1) * 64;
        unsigned short* dst = geP + (size_t)(m0 + row) * 768 + n0 + cg;
        const unsigned short* src = smem + row * 136 + cg;
        #pragma unroll
        for (int j = 0; j < 8; j++)
            *reinterpret_cast<u16x8*>(dst + j * 8) =
                *reinterpret_cast<const u16x8*>(src + j * 8);
    }
}

// ---------------- fully-independent per-b recurrence: ONE launch, zero inter-block sync ----------------
__global__ void __launch_bounds__(1024) k_loop3(
        const unsigned short* __restrict__ ep_t, const unsigned short* __restrict__ geP,
        const unsigned short* __restrict__ wA_bf, const unsigned short* __restrict__ ow_bf,
        const unsigned short* __restrict__ Wg2T, const float* __restrict__ giE,
        const float* __restrict__ attn_b, const float* __restrict__ attn_v,
        const float* __restrict__ out_b, const float* __restrict__ bhh,
        const int* __restrict__ dec_tgt, const int* __restrict__ word_tgt,
        float* __restrict__ nllG) {
    const int b = blockIdx.x;
    const int tid = threadIdx.x;
    const int hwid = tid >> 5, l32 = tid & 31;

    __shared__ float hS_f[256];
    __shared__ unsigned short hS_bf[256], hp_bf[256], v_bf[256];
    __shared__ float scr[256];
    __shared__ float gi_s[768], gh_s[768];
    __shared__ float red[16];
    __shared__ float nllA[1];

    if (tid < 256) v_bf[tid] = f2bf(attn_v[tid]);
    if (tid == 0) nllA[0] = 0.f;

    for (int t = 0; t <= T; t++) {
        __syncthreads();
        // ---- s0: GRU pointwise h_t from gi_s/gh_s of step t-1 ----
        if (tid < 256) {
            float h;
            if (t == 0) {
                h = 0.f;
            } else {
                float hold = hS_f[tid];
                int tokp = (t == 1) ? 0 : dec_tgt[b * T + (t - 2)];
                const float* gE = giE + (size_t)tokp * 768;
                float r_ = fast_sigm(gi_s[tid] + gE[tid] + gh_s[tid] + bhh[tid]);
                float z_ = fast_sigm(gi_s[256 + tid] + gE[256 + tid] + gh_s[256 + tid] + bhh[256 + tid]);
                float n_ = fast_tanh(gi_s[512 + tid] + gE[512 + tid] + r_ * (gh_s[512 + tid] + bhh[512 + tid]));
                h = (1.f - z_) * n_ + z_ * hold;
            }
            hS_f[tid] = h;
            hS_bf[tid] = f2bf(h);
        }
        __syncthreads();

        // ---- s1 (t>0): logits(h_t) + nll vs word_targets[t-1] ----
        if (t > 0) {
            #pragma unroll
            for (int it = 0; it < 6; it++) {
                int row = it * 32 + hwid;
                float d = 0.f;
                if (row < NC) {
                    u16x8 w = *reinterpret_cast<const u16x8*>(ow_bf + (size_t)row * 256 + l32 * 8);
                    u16x8 hh = *reinterpret_cast<const u16x8*>(hS_bf + l32 * 8);
                    #pragma unroll
                    for (int j = 0; j < 8; j++) d += bf2f(w[j]) * bf2f(hh[j]);
                }
                d = half_red_sum(d);
                if (l32 == 0 && row < NC) scr[row] = d + out_b[row];
            }
            __syncthreads();
            float lg = -1e30f;
            if (tid < 256) {
                if (tid < NC) lg = scr[tid];
                float m = wave_red_max(lg);
                if ((tid & 63) == 0) red[tid >> 6] = m;
            }
            __syncthreads();
            float M = fmaxf(fmaxf(red[0], red[1]), fmaxf(red[2], red[3]));
            if (tid < 256) {
                float e = (tid < NC) ? __expf(lg - M) : 0.f;
                float sm = wave_red_sum(e);
                if ((tid & 63) == 0) red[8 + (tid >> 6)] = sm;
            }
            __syncthreads();
            if (tid == 0) {
                float S = red[8] + red[9] + red[10] + red[11];
                int tgt = word_tgt[b * T + (t - 1)];
                if (tgt >= 0) nllA[0] += M + __logf(S) - scr[tgt];
            }
            __syncthreads();
        }
        if (t == T) break;

        // ---- s2: hp = h @ Wh^T + attn_b ----
        #pragma unroll
        for (int it = 0; it < 8; it++) {
            int row = it * 32 + hwid;
            u16x8 w = *reinterpret_cast<const u16x8*>(wA_bf + (size_t)row * 256 + l32 * 8);
            u16x8 hh = *reinterpret_cast<const u16x8*>(hS_bf + l32 * 8);
            float d = 0.f;
            #pragma unroll
            for (int j = 0; j < 8; j++) d += bf2f(w[j]) * bf2f(hh[j]);
            d = half_red_sum(d);
            if (l32 == 0) hp_bf[row] = f2bf(d + attn_b[row]);
        }
        __syncthreads();

        // ---- s3: scores over l → softmax weights (float, unnormalized) in scr ----
        #pragma unroll
        for (int it = 0; it < 8; it++) {
            int row = it * 32 + hwid;
            u16x8 e = *reinterpret_cast<const u16x8*>(ep_t + ((size_t)b * L + row) * 256 + l32 * 8);
            u16x8 hp = *reinterpret_cast<const u16x8*>(hp_bf + l32 * 8);
            u16x8 vv = *reinterpret_cast<const u16x8*>(v_bf + l32 * 8);
            float d = 0.f;
            #pragma unroll
            for (int j = 0; j < 8; j++)
                d += bf2f(vv[j]) * fast_tanh(bf2f(e[j]) + bf2f(hp[j]));
            d = half_red_sum(d);
            if (l32 == 0) scr[row] = d;
        }
        __syncthreads();
        float sc = -1e30f;
        if (tid < 256) {
            sc = scr[tid];
            float m = wave_red_max(sc);
            if ((tid & 63) == 0) red[tid >> 6] = m;
        }
        __syncthreads();
        float M2 = fmaxf(fmaxf(red[0], red[1]), fmaxf(red[2], red[3]));
        float e2 = 0.f;
        if (tid < 256) {
            e2 = __expf(sc - M2);
            float sm = wave_red_sum(e2);
            if ((tid & 63) == 0) red[8 + (tid >> 6)] = sm;
        }
        __syncthreads();
        if (tid < 256) scr[tid] = e2;       // scr now holds softmax numerators
        float invS = __builtin_amdgcn_rcpf(red[8] + red[9] + red[10] + red[11]);
        __syncthreads();

        // ---- s4+s5 fused: gates (column-per-thread, lane-coalesced 2B streams) ----
        // gi_ctx[g] = invS * Σ_l scr[l]·geP[b*L+l][g];  gh[g] = Σ_k h[k]·Wg2T[k][g]
        if (tid < 768) {
            const unsigned short* gp = geP + (size_t)b * L * 768 + tid;
            const unsigned short* wp = Wg2T + tid;
            float ac = 0.f, ah = 0.f;
            #pragma unroll 8
            for (int l = 0; l < 256; l++) {
                ac += scr[l] * bf2f(gp[(size_t)l * 768]);
                ah += hS_f[l] * bf2f(wp[(size_t)l * 768]);
            }
            gi_s[tid] = ac * invS;
            gh_s[tid] = ah;
        }
    }

    if (tid == 0) nllG[b] = nllA[0];
}

// ---------------- loss = 0.2 * mean_b(nll) ----------------
__global__ void k_reduce(const float* __restrict__ nll, float* __restrict__ out) {
    __shared__ float red[2];
    float v = nll[threadIdx.x];
    v = wave_red_sum(v);
    if ((threadIdx.x & 63) == 0) red[threadIdx.x >> 6] = v;
    __syncthreads();
    if (threadIdx.x == 0) out[0] = 0.2f * (red[0] + red[1]) * (1.f / 128.f);
}

extern "C" void kernel_launch(void* const* d_in, const int* in_sizes, int n_in,
                              void* d_out, int out_size, void* d_ws, size_t ws_size,
                              hipStream_t stream) {
    const float* x        = (const float*)d_in[0];
    const int*   dec_tgt  = (const int*)d_in[1];
    const int*   word_tgt = (const int*)d_in[2];
    const float* conv_w   = (const float*)d_in[3];
    const float* conv_b   = (const float*)d_in[4];
    const float* emb_dec  = (const float*)d_in[5];
    const float* word_w   = (const float*)d_in[6];
    const float* word_b   = (const float*)d_in[7];
    const float* attn_w   = (const float*)d_in[8];
    const float* attn_b   = (const float*)d_in[9];
    const float* attn_v   = (const float*)d_in[10];
    const float* gru_wih  = (const float*)d_in[11];
    const float* gru_bih  = (const float*)d_in[12];
    const float* gru_whh  = (const float*)d_in[13];
    const float* gru_bhh  = (const float*)d_in[14];
    const float* out_w    = (const float*)d_in[15];
    const float* out_b    = (const float*)d_in[16];
    const float* x_emb    = (const float*)d_in[17];
    const float* y_emb    = (const float*)d_in[18];

    char* ws = (char*)d_ws;
    size_t off = 0;
    auto alloc = [&](size_t bytes) -> void* {
        void* p = ws + off;
        off = (off + bytes + 255) & ~(size_t)255;
        return p;
    };
    unsigned short* Xt     = (unsigned short*)alloc((size_t)B * 16 * 64 * 256 * 2);   // 64MiB
    unsigned short* enc_bf = (unsigned short*)alloc((size_t)B * L * CENC * 2 + 64);   // +slack for k_gep overread
    unsigned short* Wt     = (unsigned short*)alloc((size_t)9 * 256 * 256 * 2);
    float* E      = (float*)alloc((size_t)NC * HID * 4);
    unsigned short* wA_bf  = (unsigned short*)alloc((size_t)HID * HID * 2);
    unsigned short* ow_bf  = (unsigned short*)alloc((size_t)NC * HID * 2);
    unsigned short* Wg1n   = (unsigned short*)alloc((size_t)768 * 320 * 2);
    unsigned short* Wg2T   = (unsigned short*)alloc((size_t)256 * 768 * 2);
    unsigned short* WgE    = (unsigned short*)alloc((size_t)256 * 768 * 2);
    float* giE    = (float*)alloc((size_t)NC * 768 * 4);
    float* nllG   = (float*)alloc((size_t)B * 4);
    // ep_t (16MiB) + geP (48MiB) alias Xt (dead after k_convmm)
    unsigned short* ep_t = Xt;
    unsigned short* geP  = Xt + (size_t)B * L * HID;
    float* out    = (float*)d_out;

    hipLaunchKernelGGL(k_upsxt, dim3(16, 128), dim3(256), 0, stream, x, Xt);
    hipLaunchKernelGGL(k_wt, dim3(2304), dim3(256), 0, stream, conv_w, Wt);
    hipLaunchKernelGGL(k_encpos, dim3(128), dim3(256), 0, stream, x_emb, y_emb, enc_bf);
    hipLaunchKernelGGL(k_convmm, dim3(1024, 2), dim3(256), 0, stream, Xt, Wt, conv_b, enc_bf);
    hipLaunchKernelGGL(k_etab, dim3(163), dim3(256), 0, stream, emb_dec, word_w, word_b, E);
    hipLaunchKernelGGL(k_prep, dim3(256), dim3(256), 0, stream, attn_w, out_w, wA_bf, ow_bf);
    hipLaunchKernelGGL(k_wg, dim3(768), dim3(576), 0, stream, gru_wih, gru_whh, Wg1n, Wg2T);
    hipLaunchKernelGGL(k_wge, dim3(256), dim3(768), 0, stream, gru_wih, WgE);
    hipLaunchKernelGGL(k_gie, dim3(163), dim3(768), 0, stream, E, WgE, gru_bih, giE);
    hipLaunchKernelGGL(k_ep, dim3(2, 8, 128), dim3(256), 0, stream, enc_bf, attn_w, ep_t);
    hipLaunchKernelGGL(k_gep, dim3(256, 6), dim3(256), 0, stream, enc_bf, Wg1n, geP);
    hipLaunchKernelGGL(k_loop3, dim3(128), dim3(1024), 0, stream,
                       ep_t, geP, wA_bf, ow_bf, Wg2T, giE, attn_b, attn_v,
                       out_b, gru_bhh, dec_tgt, word_tgt, nllG);
    hipLaunchKernelGGL(k_reduce, dim3(1), dim3(128), 0, stream, nllG, out);
}

// Round 10
// 3008.595 us; speedup vs baseline: 1.0201x; 1.0201x over previous
//
#include <hip/hip_runtime.h>
#include <hip/hip_bf16.h>
#include <math.h>

#define B    128
#define CIN  256
#define HIN  8
#define WIN_ 32
#define RH   16
#define RW   64
#define HID  256
#define NC   163
#define T    32
#define L    256
#define CENC 296

typedef __attribute__((ext_vector_type(8))) short short8;
typedef __attribute__((ext_vector_type(8))) unsigned short u16x8;
typedef __attribute__((ext_vector_type(4))) float f32x4;

__device__ __forceinline__ float bf2f(unsigned short u) {
    unsigned int x = ((unsigned int)u) << 16;
    return __uint_as_float(x);
}
__device__ __forceinline__ unsigned short f2bf(float f) {
    unsigned int x = __float_as_uint(f);
    unsigned int r = (x + 0x7FFFu + ((x >> 16) & 1u)) >> 16;
    return (unsigned short)r;
}
// fp8 e4m3 (OCP) encode/decode via HW converts
__device__ __forceinline__ unsigned char f2f8(float f) {
    int r = __builtin_amdgcn_cvt_pk_fp8_f32(f, 0.f, 0, false);
    return (unsigned char)(r & 0xff);
}
__device__ __forceinline__ float4 f8x4(unsigned int u) {
    auto lo = __builtin_amdgcn_cvt_pk_f32_fp8((int)u, false);
    auto hi = __builtin_amdgcn_cvt_pk_f32_fp8((int)u, true);
    return make_float4(lo[0], lo[1], hi[0], hi[1]);
}
__device__ __forceinline__ float fast_tanh(float x) {
    float e = __expf(2.f * x);
    return 1.f - 2.f * __builtin_amdgcn_rcpf(e + 1.f);
}
__device__ __forceinline__ float fast_sigm(float x) {
    return __builtin_amdgcn_rcpf(1.f + __expf(-x));
}
__device__ __forceinline__ float wave_red_max(float v) {
    #pragma unroll
    for (int o = 32; o > 0; o >>= 1) v = fmaxf(v, __shfl_down(v, o, 64));
    return v;
}
__device__ __forceinline__ float wave_red_sum(float v) {
    #pragma unroll
    for (int o = 32; o > 0; o >>= 1) v += __shfl_down(v, o, 64);
    return v;
}
__device__ __forceinline__ float half_red_sum(float v) {
    #pragma unroll
    for (int o = 16; o > 0; o >>= 1) v += __shfl_down(v, o, 64);
    return v;
}

// ---------------- bilinear upsample fused with transpose → Xt[b][y][x][ci] bf16 ----------------
__global__ void __launch_bounds__(256) k_upsxt(const float* __restrict__ x,
                                               unsigned short* __restrict__ Xt) {
    __shared__ __align__(16) float sf[64 * 2 * 32];
    const int y = blockIdx.x;
    const int b = blockIdx.y;
    const int tid = threadIdx.x;
    float sy = 0.5f * y - 0.25f;
    int yq0 = (y - 1) >> 1;
    float wy = sy - (float)yq0;
    int y0c = min(max(yq0, 0), HIN - 1);
    int y1c = min(max(yq0 + 1, 0), HIN - 1);
    const int xo = tid & 63;
    const int cj = tid >> 6;
    float sx = 0.5f * xo - 0.25f;
    int xq0 = (xo - 1) >> 1;
    float wx = sx - (float)xq0;
    int x0c = min(max(xq0, 0), WIN_ - 1);
    int x1c = min(max(xq0 + 1, 0), WIN_ - 1);
    for (int cc = 0; cc < 4; cc++) {
        __syncthreads();
        #pragma unroll
        for (int i = 0; i < 4; i++) {
            int idx = tid * 4 + i;
            int c = idx >> 4;
            int rowh = (idx >> 3) & 1;
            int part = idx & 7;
            int ysrc = rowh ? y1c : y0c;
            float4 v = *reinterpret_cast<const float4*>(
                x + ((size_t)(b * CIN + cc * 64 + c) * HIN + ysrc) * WIN_ + part * 4);
            *reinterpret_cast<float4*>(sf + ((c * 2 + rowh) * 32 + part * 4)) = v;
        }
        __syncthreads();
        unsigned short ov[16];
        #pragma unroll
        for (int j = 0; j < 16; j++) {
            int c = cj * 16 + j;
            const float* r0 = sf + (c * 2 + 0) * 32;
            const float* r1 = sf + (c * 2 + 1) * 32;
            float v = (1.f - wy) * ((1.f - wx) * r0[x0c] + wx * r0[x1c])
                    +        wy  * ((1.f - wx) * r1[x0c] + wx * r1[x1c]);
            ov[j] = f2bf(v);
        }
        unsigned short* dst = Xt + ((size_t)((b * 16 + y) * 64 + xo)) * 256 + cc * 64 + cj * 16;
        *reinterpret_cast<u16x8*>(dst)     = *reinterpret_cast<u16x8*>(ov);
        *reinterpret_cast<u16x8*>(dst + 8) = *reinterpret_cast<u16x8*>(ov + 8);
    }
}

// ---------------- weight transform: Wt[s][co][ci] bf16 ----------------
__global__ void k_wt(const float* __restrict__ conv_w, unsigned short* __restrict__ Wt) {
    int e = blockIdx.x * 256 + threadIdx.x;
    int ci = e & 255;
    int co = (e >> 8) & 255;
    int s  = e >> 16;
    Wt[(size_t)(s * 256 + co) * 256 + ci] = f2bf(conv_w[(size_t)(co * 256 + ci) * 9 + s]);
}

// ---------------- conv3x3 MFMA implicit GEMM + fused bias/ReLU/pool → enc_bf ----------------
__global__ void __launch_bounds__(256) k_convmm(const unsigned short* __restrict__ Xt,
        const unsigned short* __restrict__ Wt, const float* __restrict__ conv_b,
        unsigned short* __restrict__ enc_bf) {
    __shared__ __align__(16) char smem[34048];
    unsigned short* A_s = (unsigned short*)smem;
    unsigned short* B_s = A_s + 128 * 40;
    float* pool = (float*)smem;
    const int mt = blockIdx.x;
    const int n0 = blockIdx.y * 128;
    const int b = mt >> 3;
    const int y0 = (mt & 7) * 2;
    const int tid = threadIdx.x;
    const int wave = tid >> 6, lane = tid & 63;
    const int mq = (wave & 1) * 64, nq = (wave >> 1) * 64;
    const int lm = lane & 15, lq = lane >> 4;
    f32x4 acc[4][4];
    #pragma unroll
    for (int mi = 0; mi < 4; mi++)
        #pragma unroll
        for (int ni = 0; ni < 4; ni++)
            #pragma unroll
            for (int r = 0; r < 4; r++) acc[mi][ni][r] = 0.f;

    for (int s9 = 0; s9 < 9; s9++) {
        const int ky = s9 / 3, kx = s9 % 3;
        const unsigned short* Wb = Wt + (size_t)s9 * 256 * 256;
        for (int kc = 0; kc < 256; kc += 32) {
            __syncthreads();
            #pragma unroll
            for (int it = 0; it < 2; it++) {
                int s2 = tid + it * 256;
                int pix = s2 >> 2, q4 = s2 & 3;
                int yy = y0 + (pix >> 6) + ky - 1;
                int xx = (pix & 63) + kx - 1;
                u16x8 va = {0, 0, 0, 0, 0, 0, 0, 0};
                if ((unsigned)yy < 16u && (unsigned)xx < 64u)
                    va = *reinterpret_cast<const u16x8*>(
                        Xt + ((size_t)((b * 16 + yy) * 64 + xx)) * 256 + kc + q4 * 8);
                *reinterpret_cast<u16x8*>(A_s + pix * 40 + q4 * 8) = va;
                u16x8 vb = *reinterpret_cast<const u16x8*>(
                    Wb + (size_t)(n0 + pix) * 256 + kc + q4 * 8);
                *reinterpret_cast<u16x8*>(B_s + pix * 40 + q4 * 8) = vb;
            }
            __syncthreads();
            short8 af[4], bfr[4];
            #pragma unroll
            for (int mi = 0; mi < 4; mi++)
                af[mi] = *reinterpret_cast<const short8*>(A_s + (mq + mi * 16 + lm) * 40 + lq * 8);
            #pragma unroll
            for (int ni = 0; ni < 4; ni++)
                bfr[ni] = *reinterpret_cast<const short8*>(B_s + (nq + ni * 16 + lm) * 40 + lq * 8);
            #pragma unroll
            for (int mi = 0; mi < 4; mi++)
                #pragma unroll
                for (int ni = 0; ni < 4; ni++)
                    acc[mi][ni] = __builtin_amdgcn_mfma_f32_16x16x32_bf16(
                        af[mi], bfr[ni], acc[mi][ni], 0, 0, 0);
        }
    }
    __syncthreads();
    #pragma unroll
    for (int mi = 0; mi < 4; mi++) {
        int px0 = mi * 8 + lq * 2;
        #pragma unroll
        for (int ni = 0; ni < 4; ni++) {
            int nl = nq + ni * 16 + lm;
            float pa = fmaxf(acc[mi][ni][0], acc[mi][ni][1]);
            float pb = fmaxf(acc[mi][ni][2], acc[mi][ni][3]);
            pool[((wave & 1) * 32 + px0) * 132 + nl] = pa;
            pool[((wave & 1) * 32 + px0 + 1) * 132 + nl] = pb;
        }
    }
    __syncthreads();
    {
        int base = tid * 16;
        int px = base >> 7;
        int nb = base & 127;
        unsigned short ov[16];
        #pragma unroll
        for (int i = 0; i < 16; i++) {
            int n = nb + i;
            float v = fmaxf(pool[px * 132 + n], pool[(32 + px) * 132 + n]) + conv_b[n0 + n];
            ov[i] = f2bf(fmaxf(v, 0.f));
        }
        unsigned short* dst = enc_bf + ((size_t)b * L + (mt & 7) * 32 + px) * CENC + n0 + nb;
        *reinterpret_cast<u16x8*>(dst)     = *reinterpret_cast<u16x8*>(ov);
        *reinterpret_cast<u16x8*>(dst + 8) = *reinterpret_cast<u16x8*>(ov + 8);
    }
}

// ---------------- positional channels 256..295 (bf16) + pos2t[40][256] bf16 ----------------
__global__ void k_encpos(const float* __restrict__ x_emb, const float* __restrict__ y_emb,
                         unsigned short* __restrict__ enc_bf, unsigned short* __restrict__ pos2t) {
    int b = blockIdx.x, l = threadIdx.x;
    int yl = l >> 5, xl = l & 31;
    unsigned short* e = enc_bf + (size_t)(b * L + l) * CENC + 256;
    #pragma unroll
    for (int c = 0; c < 32; c++) e[c] = f2bf(x_emb[xl * 32 + c]);
    #pragma unroll
    for (int c = 0; c < 8; c++) e[32 + c] = f2bf(y_emb[yl * 8 + c]);
    if (b == 0) {
        #pragma unroll
        for (int c = 0; c < 32; c++) pos2t[c * 256 + l] = f2bf(x_emb[xl * 32 + c]);
        #pragma unroll
        for (int c = 0; c < 8; c++) pos2t[(32 + c) * 256 + l] = f2bf(y_emb[yl * 8 + c]);
    }
}

// ---------------- enc_tf8[b][c][l] fp8 (c<256) ----------------
__global__ void __launch_bounds__(256) k_enctf8(const unsigned short* __restrict__ enc_bf,
                                                unsigned char* __restrict__ enc_tf8) {
    __shared__ unsigned short s[64 * 264];
    const int c0 = blockIdx.x * 64;
    const int b = blockIdx.y;
    const int tid = threadIdx.x;
    #pragma unroll
    for (int j = 0; j < 8; j++) {
        u16x8 u = *reinterpret_cast<const u16x8*>(
            enc_bf + ((size_t)b * L + tid) * CENC + c0 + j * 8);
        #pragma unroll
        for (int k = 0; k < 8; k++) s[(j * 8 + k) * 264 + tid] = u[k];
    }
    __syncthreads();
    {
        int c = tid >> 2, lp = tid & 3;
        const unsigned short* row = s + c * 264 + lp * 64;
        unsigned char* dst = enc_tf8 + ((size_t)b * 256 + c0 + c) * 256 + lp * 64;
        #pragma unroll
        for (int i = 0; i < 8; i++) {
            unsigned char ob[8];
            #pragma unroll
            for (int j = 0; j < 8; j++) ob[j] = f2f8(bf2f(row[i * 8 + j]));
            *reinterpret_cast<uint2*>(dst + i * 8) = *reinterpret_cast<uint2*>(ob);
        }
    }
}

// ---------------- E[v][h] fp32 ----------------
__global__ void __launch_bounds__(256) k_etab(const float* __restrict__ emb_dec,
                                              const float* __restrict__ word_w,
                                              const float* __restrict__ word_b,
                                              float* __restrict__ E) {
    __shared__ float er[NC];
    int row = blockIdx.x, tid = threadIdx.x;
    for (int k = tid; k < NC; k += 256) er[k] = emb_dec[(size_t)row * NC + k];
    __syncthreads();
    float a = word_b[tid];
    for (int k = 0; k < NC; k++) a += er[k] * word_w[(size_t)tid * NC + k];
    E[(size_t)row * HID + tid] = a;
}

// ---------------- fp8 weight casts: wA_f8[256][256], ow_f8[163][256] ----------------
__global__ void k_prep(const float* __restrict__ attn_w, const float* __restrict__ out_w,
                       unsigned char* __restrict__ wA_f8, unsigned char* __restrict__ ow_f8) {
    int o = blockIdx.x, k = threadIdx.x;
    wA_f8[(size_t)o * 256 + k] = f2f8(attn_w[(size_t)o * 552 + k]);
    if (o < NC) ow_f8[(size_t)o * 256 + k] = f2f8(out_w[(size_t)o * 256 + k]);
}

// ---------------- GRU weights fp8, k-major: Wg1T[k<320][g], Wg2T[k<256][g] ----------------
__global__ void __launch_bounds__(768) k_wg(const float* __restrict__ wih,
                                            const float* __restrict__ whh,
                                            unsigned char* __restrict__ Wg1T,
                                            unsigned char* __restrict__ Wg2T) {
    int kidx = blockIdx.x, g = threadIdx.x;
    if (kidx < 320) {
        float v = (kidx < 296) ? wih[(size_t)g * 552 + 256 + kidx] : 0.f;
        Wg1T[(size_t)kidx * 768 + g] = f2f8(v);
    } else {
        int k2 = kidx - 320;
        Wg2T[(size_t)k2 * 768 + g] = f2f8(whh[(size_t)g * 256 + k2]);
    }
}
__global__ void __launch_bounds__(768) k_wge(const float* __restrict__ wih,
                                             unsigned short* __restrict__ WgE) {
    int k = blockIdx.x, g = threadIdx.x;
    WgE[(size_t)k * 768 + g] = f2bf(wih[(size_t)g * 552 + k]);
}
// giE[v][g] = emb-part of gi + bih
__global__ void __launch_bounds__(768) k_gie(const float* __restrict__ E,
                                             const unsigned short* __restrict__ WgE,
                                             const float* __restrict__ bih,
                                             float* __restrict__ giE) {
    __shared__ float er[256];
    int v = blockIdx.x, g = threadIdx.x;
    if (g < 256) er[g] = E[(size_t)v * 256 + g];
    __syncthreads();
    float a = bih[g];
    #pragma unroll 4
    for (int k = 0; k < 256; k++) a += er[k] * bf2f(WgE[(size_t)k * 768 + g]);
    giE[(size_t)v * 768 + g] = a;
}

// ---------------- ep_t[b][l][h] bf16 ----------------
__global__ void __launch_bounds__(256) k_ep(const unsigned short* __restrict__ enc_bf,
                                            const float* __restrict__ attn_w,
                                            unsigned short* __restrict__ ep_t) {
    __shared__ __align__(16) float eS[16][132];
    __shared__ __align__(16) float wS[16][36];
    const int l0 = blockIdx.x * 128;
    const int h0 = blockIdx.y * 32;
    const int b = blockIdx.z;
    const int tid = threadIdx.x;
    const int hh = tid >> 5, ll = tid & 31;
    float acc[4][4];
    #pragma unroll
    for (int s2 = 0; s2 < 4; s2++)
        #pragma unroll
        for (int r = 0; r < 4; r++) acc[s2][r] = 0.f;
    for (int kc = 0; kc < CENC; kc += 16) {
        const int kn = min(16, CENC - kc);
        __syncthreads();
        #pragma unroll
        for (int it = 0; it < 2; it++) {
            int idx = it * 256 + tid;
            int lq = idx >> 2, kq = idx & 3;
            float v0 = 0.f, v1 = 0.f, v2 = 0.f, v3 = 0.f;
            if (kq * 4 < kn) {
                ushort4 u = *reinterpret_cast<const ushort4*>(
                    enc_bf + (size_t)(b * L + l0 + lq) * CENC + kc + kq * 4);
                v0 = bf2f(u.x); v1 = bf2f(u.y); v2 = bf2f(u.z); v3 = bf2f(u.w);
            }
            eS[kq * 4 + 0][lq] = v0; eS[kq * 4 + 1][lq] = v1;
            eS[kq * 4 + 2][lq] = v2; eS[kq * 4 + 3][lq] = v3;
        }
        if (tid < 128) {
            int hq = tid >> 2, kq = tid & 3;
            float4 v = make_float4(0.f, 0.f, 0.f, 0.f);
            if (kq * 4 < kn)
                v = *reinterpret_cast<const float4*>(attn_w + (size_t)(h0 + hq) * 552 + 256 + kc + kq * 4);
            wS[kq * 4 + 0][hq] = v.x; wS[kq * 4 + 1][hq] = v.y;
            wS[kq * 4 + 2][hq] = v.z; wS[kq * 4 + 3][hq] = v.w;
        }
        __syncthreads();
        #pragma unroll
        for (int k = 0; k < 16; k++) {
            float4 e = *reinterpret_cast<const float4*>(&eS[k][ll * 4]);
            float4 w = *reinterpret_cast<const float4*>(&wS[k][hh * 4]);
            float ev[4] = {e.x, e.y, e.z, e.w};
            float wv[4] = {w.x, w.y, w.z, w.w};
            #pragma unroll
            for (int s2 = 0; s2 < 4; s2++)
                #pragma unroll
                for (int r = 0; r < 4; r++) acc[s2][r] += wv[s2] * ev[r];
        }
    }
    #pragma unroll
    for (int r = 0; r < 4; r++) {
        ushort4 o;
        o.x = f2bf(acc[0][r]); o.y = f2bf(acc[1][r]);
        o.z = f2bf(acc[2][r]); o.w = f2bf(acc[3][r]);
        *reinterpret_cast<ushort4*>(
            ep_t + ((size_t)(b * L) + l0 + ll * 4 + r) * HID + h0 + hh * 4) = o;
    }
}

// ---------------- fully-independent per-b recurrence, L2-resident fp8 operands ----------------
__global__ void __launch_bounds__(1024) k_loop3(
        const unsigned short* __restrict__ ep_t, const unsigned char* __restrict__ enc_tf8,
        const unsigned char* __restrict__ wA_f8, const unsigned char* __restrict__ ow_f8,
        const unsigned char* __restrict__ Wg1T, const unsigned char* __restrict__ Wg2T,
        const float* __restrict__ giE, const unsigned short* __restrict__ pos2t,
        const float* __restrict__ attn_b, const float* __restrict__ attn_v,
        const float* __restrict__ out_b, const float* __restrict__ bhh,
        const int* __restrict__ dec_tgt, const int* __restrict__ word_tgt,
        float* __restrict__ nllG) {
    const int b = blockIdx.x;
    const int tid = threadIdx.x;
    const int hwid = tid >> 5, l32 = tid & 31;

    __shared__ float hS_f[256];
    __shared__ unsigned short hS_bf[256], hp_bf[256], v_bf[256], s_bf[256];
    __shared__ float scr[256];
    __shared__ float ctx_s[320];
    __shared__ float gi_s[768], gh_s[768];
    __shared__ float part1[5][768];
    __shared__ float part2[4][768];
    __shared__ float red[16];
    __shared__ float nllA[1];

    if (tid < 256) v_bf[tid] = f2bf(attn_v[tid]);
    if (tid >= 296 && tid < 320) ctx_s[tid] = 0.f;   // K-pad (never rewritten)
    if (tid == 0) nllA[0] = 0.f;

    for (int t = 0; t <= T; t++) {
        __syncthreads();
        // ---- s0: GRU pointwise h_t from gi_s/gh_s of step t-1 ----
        if (tid < 256) {
            float h;
            if (t == 0) {
                h = 0.f;
            } else {
                float hold = hS_f[tid];
                int tokp = (t == 1) ? 0 : dec_tgt[b * T + (t - 2)];
                const float* gE = giE + (size_t)tokp * 768;
                float r_ = fast_sigm(gi_s[tid] + gE[tid] + gh_s[tid] + bhh[tid]);
                float z_ = fast_sigm(gi_s[256 + tid] + gE[256 + tid] + gh_s[256 + tid] + bhh[256 + tid]);
                float n_ = fast_tanh(gi_s[512 + tid] + gE[512 + tid] + r_ * (gh_s[512 + tid] + bhh[512 + tid]));
                h = (1.f - z_) * n_ + z_ * hold;
            }
            hS_f[tid] = h;
            hS_bf[tid] = f2bf(h);
        }
        __syncthreads();

        // ---- s1 (t>0): logits(h_t) + nll vs word_targets[t-1] ----
        if (t > 0) {
            #pragma unroll
            for (int it = 0; it < 6; it++) {
                int row = it * 32 + hwid;
                float d = 0.f;
                if (row < NC) {
                    uint2 w8 = *reinterpret_cast<const uint2*>(ow_f8 + (size_t)row * 256 + l32 * 8);
                    u16x8 hh = *reinterpret_cast<const u16x8*>(hS_bf + l32 * 8);
                    float4 fa = f8x4(w8.x), fb = f8x4(w8.y);
                    d = fa.x * bf2f(hh[0]) + fa.y * bf2f(hh[1]) + fa.z * bf2f(hh[2]) + fa.w * bf2f(hh[3])
                      + fb.x * bf2f(hh[4]) + fb.y * bf2f(hh[5]) + fb.z * bf2f(hh[6]) + fb.w * bf2f(hh[7]);
                }
                d = half_red_sum(d);
                if (l32 == 0 && row < NC) scr[row] = d + out_b[row];
            }
            __syncthreads();
            float lg = -1e30f;
            if (tid < 256) {
                if (tid < NC) lg = scr[tid];
                float m = wave_red_max(lg);
                if ((tid & 63) == 0) red[tid >> 6] = m;
            }
            __syncthreads();
            float M = fmaxf(fmaxf(red[0], red[1]), fmaxf(red[2], red[3]));
            if (tid < 256) {
                float e = (tid < NC) ? __expf(lg - M) : 0.f;
                float sm = wave_red_sum(e);
                if ((tid & 63) == 0) red[8 + (tid >> 6)] = sm;
            }
            __syncthreads();
            if (tid == 0) {
                float S = red[8] + red[9] + red[10] + red[11];
                int tgt = word_tgt[b * T + (t - 1)];
                if (tgt >= 0) nllA[0] += M + __logf(S) - scr[tgt];
            }
            __syncthreads();
        }
        if (t == T) break;

        // ---- s2: hp = h @ Wh^T + attn_b ----
        #pragma unroll
        for (int it = 0; it < 8; it++) {
            int row = it * 32 + hwid;
            uint2 w8 = *reinterpret_cast<const uint2*>(wA_f8 + (size_t)row * 256 + l32 * 8);
            u16x8 hh = *reinterpret_cast<const u16x8*>(hS_bf + l32 * 8);
            float4 fa = f8x4(w8.x), fb = f8x4(w8.y);
            float d = fa.x * bf2f(hh[0]) + fa.y * bf2f(hh[1]) + fa.z * bf2f(hh[2]) + fa.w * bf2f(hh[3])
                    + fb.x * bf2f(hh[4]) + fb.y * bf2f(hh[5]) + fb.z * bf2f(hh[6]) + fb.w * bf2f(hh[7]);
            d = half_red_sum(d);
            if (l32 == 0) hp_bf[row] = f2bf(d + attn_b[row]);
        }
        __syncthreads();

        // ---- s3: scores over l ----
        #pragma unroll
        for (int it = 0; it < 8; it++) {
            int row = it * 32 + hwid;
            u16x8 e = *reinterpret_cast<const u16x8*>(ep_t + ((size_t)b * L + row) * 256 + l32 * 8);
            u16x8 hp = *reinterpret_cast<const u16x8*>(hp_bf + l32 * 8);
            u16x8 vv = *reinterpret_cast<const u16x8*>(v_bf + l32 * 8);
            float d = 0.f;
            #pragma unroll
            for (int j = 0; j < 8; j++)
                d += bf2f(vv[j]) * fast_tanh(bf2f(e[j]) + bf2f(hp[j]));
            d = half_red_sum(d);
            if (l32 == 0) scr[row] = d;
        }
        __syncthreads();
        float sc = -1e30f;
        if (tid < 256) {
            sc = scr[tid];
            float m = wave_red_max(sc);
            if ((tid & 63) == 0) red[tid >> 6] = m;
        }
        __syncthreads();
        float M2 = fmaxf(fmaxf(red[0], red[1]), fmaxf(red[2], red[3]));
        if (tid < 256) {
            float e2 = __expf(sc - M2);
            s_bf[tid] = f2bf(e2);
            float sm = wave_red_sum(e2);
            if ((tid & 63) == 0) red[8 + (tid >> 6)] = sm;
        }
        __syncthreads();
        float invS = __builtin_amdgcn_rcpf(red[8] + red[9] + red[10] + red[11]);

        // ---- s4: ctx → ctx_s[0..295] (fp8 enc rows + bf16 positional rows) ----
        #pragma unroll
        for (int it = 0; it < 8; it++) {
            int row = it * 32 + hwid;
            uint2 e8 = *reinterpret_cast<const uint2*>(enc_tf8 + ((size_t)b * 256 + row) * 256 + l32 * 8);
            u16x8 ss = *reinterpret_cast<const u16x8*>(s_bf + l32 * 8);
            float4 fa = f8x4(e8.x), fb = f8x4(e8.y);
            float d = fa.x * bf2f(ss[0]) + fa.y * bf2f(ss[1]) + fa.z * bf2f(ss[2]) + fa.w * bf2f(ss[3])
                    + fb.x * bf2f(ss[4]) + fb.y * bf2f(ss[5]) + fb.z * bf2f(ss[6]) + fb.w * bf2f(ss[7]);
            d = half_red_sum(d);
            if (l32 == 0) ctx_s[row] = d * invS;
        }
        #pragma unroll
        for (int it = 0; it < 2; it++) {
            int row = it * 32 + hwid;
            float d = 0.f;
            if (row < 40) {
                u16x8 p = *reinterpret_cast<const u16x8*>(pos2t + (size_t)row * 256 + l32 * 8);
                u16x8 ss = *reinterpret_cast<const u16x8*>(s_bf + l32 * 8);
                #pragma unroll
                for (int j = 0; j < 8; j++) d += bf2f(ss[j]) * bf2f(p[j]);
            }
            d = half_red_sum(d);
            if (l32 == 0 && row < 40) ctx_s[256 + row] = d * invS;
        }
        __syncthreads();

        // ---- s5: gate GEMVs (fp8 weights, column-per-thread, K-sliced) ----
        if (tid < 960) {
            int ks = tid / 192, g0 = (tid % 192) * 4;
            float a0 = 0.f, a1 = 0.f, a2 = 0.f, a3 = 0.f;
            #pragma unroll 8
            for (int kk = 0; kk < 64; kk++) {
                int k = ks * 64 + kk;
                float c = ctx_s[k];
                unsigned int w = *reinterpret_cast<const unsigned int*>(Wg1T + (size_t)k * 768 + g0);
                float4 f = f8x4(w);
                a0 = fmaf(c, f.x, a0); a1 = fmaf(c, f.y, a1);
                a2 = fmaf(c, f.z, a2); a3 = fmaf(c, f.w, a3);
            }
            *reinterpret_cast<float4*>(&part1[ks][g0]) = make_float4(a0, a1, a2, a3);
        }
        if (tid < 768) {
            int ks = tid / 192, g0 = (tid % 192) * 4;
            float a0 = 0.f, a1 = 0.f, a2 = 0.f, a3 = 0.f;
            #pragma unroll 8
            for (int kk = 0; kk < 64; kk++) {
                int k = ks * 64 + kk;
                float hv = hS_f[k];
                unsigned int w = *reinterpret_cast<const unsigned int*>(Wg2T + (size_t)k * 768 + g0);
                float4 f = f8x4(w);
                a0 = fmaf(hv, f.x, a0); a1 = fmaf(hv, f.y, a1);
                a2 = fmaf(hv, f.z, a2); a3 = fmaf(hv, f.w, a3);
            }
            *reinterpret_cast<float4*>(&part2[ks][g0]) = make_float4(a0, a1, a2, a3);
        }
        __syncthreads();
        if (tid < 768) {
            gi_s[tid] = part1[0][tid] + part1[1][tid] + part1[2][tid] + part1[3][tid] + part1[4][tid];
            gh_s[tid] = part2[0][tid] + part2[1][tid] + part2[2][tid] + part2[3][tid];
        }
    }

    if (tid == 0) nllG[b] = nllA[0];
}

// ---------------- loss = 0.2 * mean_b(nll) ----------------
__global__ void k_reduce(const float* __restrict__ nll, float* __restrict__ out) {
    __shared__ float red[2];
    float v = nll[threadIdx.x];
    v = wave_red_sum(v);
    if ((threadIdx.x & 63) == 0) red[threadIdx.x >> 6] = v;
    __syncthreads();
    if (threadIdx.x == 0) out[0] = 0.2f * (red[0] + red[1]) * (1.f / 128.f);
}

extern "C" void kernel_launch(void* const* d_in, const int* in_sizes, int n_in,
                              void* d_out, int out_size, void* d_ws, size_t ws_size,
                              hipStream_t stream) {
    const float* x        = (const float*)d_in[0];
    const int*   dec_tgt  = (const int*)d_in[1];
    const int*   word_tgt = (const int*)d_in[2];
    const float* conv_w   = (const float*)d_in[3];
    const float* conv_b   = (const float*)d_in[4];
    const float* emb_dec  = (const float*)d_in[5];
    const float* word_w   = (const float*)d_in[6];
    const float* word_b   = (const float*)d_in[7];
    const float* attn_w   = (const float*)d_in[8];
    const float* attn_b   = (const float*)d_in[9];
    const float* attn_v   = (const float*)d_in[10];
    const float* gru_wih  = (const float*)d_in[11];
    const float* gru_bih  = (const float*)d_in[12];
    const float* gru_whh  = (const float*)d_in[13];
    const float* gru_bhh  = (const float*)d_in[14];
    const float* out_w    = (const float*)d_in[15];
    const float* out_b    = (const float*)d_in[16];
    const float* x_emb    = (const float*)d_in[17];
    const float* y_emb    = (const float*)d_in[18];

    char* ws = (char*)d_ws;
    size_t off = 0;
    auto alloc = [&](size_t bytes) -> void* {
        void* p = ws + off;
        off = (off + bytes + 255) & ~(size_t)255;
        return p;
    };
    unsigned short* Xt     = (unsigned short*)alloc((size_t)B * 16 * 64 * 256 * 2);   // 64MiB
    unsigned short* enc_bf = (unsigned short*)alloc((size_t)B * L * CENC * 2 + 64);
    unsigned short* Wt     = (unsigned short*)alloc((size_t)9 * 256 * 256 * 2);
    float* E      = (float*)alloc((size_t)NC * HID * 4);
    unsigned char* wA_f8   = (unsigned char*)alloc((size_t)HID * HID);
    unsigned char* ow_f8   = (unsigned char*)alloc((size_t)NC * HID);
    unsigned char* Wg1T    = (unsigned char*)alloc((size_t)320 * 768);
    unsigned char* Wg2T    = (unsigned char*)alloc((size_t)256 * 768);
    unsigned short* WgE    = (unsigned short*)alloc((size_t)256 * 768 * 2);
    float* giE    = (float*)alloc((size_t)NC * 768 * 4);
    unsigned char* enc_tf8 = (unsigned char*)alloc((size_t)B * 256 * 256);            // 8.4MB
    unsigned short* pos2t  = (unsigned short*)alloc((size_t)40 * 256 * 2);
    float* nllG   = (float*)alloc((size_t)B * 4);
    // ep_t (16MiB) aliases Xt (dead after k_convmm)
    unsigned short* ep_t = Xt;
    float* out    = (float*)d_out;

    hipLaunchKernelGGL(k_upsxt, dim3(16, 128), dim3(256), 0, stream, x, Xt);
    hipLaunchKernelGGL(k_wt, dim3(2304), dim3(256), 0, stream, conv_w, Wt);
    hipLaunchKernelGGL(k_encpos, dim3(128), dim3(256), 0, stream, x_emb, y_emb, enc_bf, pos2t);
    hipLaunchKernelGGL(k_convmm, dim3(1024, 2), dim3(256), 0, stream, Xt, Wt, conv_b, enc_bf);
    hipLaunchKernelGGL(k_etab, dim3(163), dim3(256), 0, stream, emb_dec, word_w, word_b, E);
    hipLaunchKernelGGL(k_prep, dim3(256), dim3(256), 0, stream, attn_w, out_w, wA_f8, ow_f8);
    hipLaunchKernelGGL(k_wg, dim3(576), dim3(768), 0, stream, gru_wih, gru_whh, Wg1T, Wg2T);
    hipLaunchKernelGGL(k_wge, dim3(256), dim3(768), 0, stream, gru_wih, WgE);
    hipLaunchKernelGGL(k_gie, dim3(163), dim3(768), 0, stream, E, WgE, gru_bih, giE);
    hipLaunchKernelGGL(k_ep, dim3(2, 8, 128), dim3(256), 0, stream, enc_bf, attn_w, ep_t);
    hipLaunchKernelGGL(k_enctf8, dim3(4, 128), dim3(256), 0, stream, enc_bf, enc_tf8);
    hipLaunchKernelGGL(k_loop3, dim3(128), dim3(1024), 0, stream,
                       ep_t, enc_tf8, wA_f8, ow_f8, Wg1T, Wg2T, giE, pos2t,
                       attn_b, attn_v, out_b, gru_bhh, dec_tgt, word_tgt, nllG);
    hipLaunchKernelGGL(k_reduce, dim3(1), dim3(128), 0, stream, nllG, out);
}

// Round 11
// 2711.992 us; speedup vs baseline: 1.1316x; 1.1094x over previous
//
#include <hip/hip_runtime.h>
#include <hip/hip_bf16.h>
#include <math.h>

#define B    128
#define CIN  256
#define HIN  8
#define WIN_ 32
#define RH   16
#define RW   64
#define HID  256
#define NC   163
#define T    32
#define L    256
#define CENC 296
#define EPL  152   // ep rows resident in LDS (must be multiple of 4)

typedef __attribute__((ext_vector_type(8))) short short8;
typedef __attribute__((ext_vector_type(8))) unsigned short u16x8;
typedef __attribute__((ext_vector_type(4))) float f32x4;

__device__ __forceinline__ float bf2f(unsigned short u) {
    unsigned int x = ((unsigned int)u) << 16;
    return __uint_as_float(x);
}
__device__ __forceinline__ unsigned short f2bf(float f) {
    unsigned int x = __float_as_uint(f);
    unsigned int r = (x + 0x7FFFu + ((x >> 16) & 1u)) >> 16;
    return (unsigned short)r;
}
__device__ __forceinline__ unsigned char f2f8(float f) {
    int r = __builtin_amdgcn_cvt_pk_fp8_f32(f, 0.f, 0, false);
    return (unsigned char)(r & 0xff);
}
__device__ __forceinline__ float4 f8x4(unsigned int u) {
    auto lo = __builtin_amdgcn_cvt_pk_f32_fp8((int)u, false);
    auto hi = __builtin_amdgcn_cvt_pk_f32_fp8((int)u, true);
    return make_float4(lo[0], lo[1], hi[0], hi[1]);
}
__device__ __forceinline__ float fast_tanh(float x) {
    float e = __expf(2.f * x);
    return 1.f - 2.f * __builtin_amdgcn_rcpf(e + 1.f);
}
__device__ __forceinline__ float fast_sigm(float x) {
    return __builtin_amdgcn_rcpf(1.f + __expf(-x));
}
__device__ __forceinline__ float wave_red_max(float v) {
    #pragma unroll
    for (int o = 32; o > 0; o >>= 1) v = fmaxf(v, __shfl_down(v, o, 64));
    return v;
}
__device__ __forceinline__ float wave_red_sum(float v) {
    #pragma unroll
    for (int o = 32; o > 0; o >>= 1) v += __shfl_down(v, o, 64);
    return v;
}
__device__ __forceinline__ float q16_red_sum(float v) {
    v += __shfl_down(v, 8, 64);
    v += __shfl_down(v, 4, 64);
    v += __shfl_down(v, 2, 64);
    v += __shfl_down(v, 1, 64);
    return v;
}
// dot of 16 fp8 (uint4) with 16 bf16 (two u16x8)
__device__ __forceinline__ float dot16_f8_bf(uint4 w8, const unsigned short* bp) {
    u16x8 h0 = *reinterpret_cast<const u16x8*>(bp);
    u16x8 h1 = *reinterpret_cast<const u16x8*>(bp + 8);
    float4 a = f8x4(w8.x), b = f8x4(w8.y), c = f8x4(w8.z), d = f8x4(w8.w);
    float s = a.x * bf2f(h0[0]) + a.y * bf2f(h0[1]) + a.z * bf2f(h0[2]) + a.w * bf2f(h0[3]);
    s += b.x * bf2f(h0[4]) + b.y * bf2f(h0[5]) + b.z * bf2f(h0[6]) + b.w * bf2f(h0[7]);
    s += c.x * bf2f(h1[0]) + c.y * bf2f(h1[1]) + c.z * bf2f(h1[2]) + c.w * bf2f(h1[3]);
    s += d.x * bf2f(h1[4]) + d.y * bf2f(h1[5]) + d.z * bf2f(h1[6]) + d.w * bf2f(h1[7]);
    return s;
}

// ---------------- bilinear upsample fused with transpose → Xt[b][y][x][ci] bf16 ----------------
__global__ void __launch_bounds__(256) k_upsxt(const float* __restrict__ x,
                                               unsigned short* __restrict__ Xt) {
    __shared__ __align__(16) float sf[64 * 2 * 32];
    const int y = blockIdx.x;
    const int b = blockIdx.y;
    const int tid = threadIdx.x;
    float sy = 0.5f * y - 0.25f;
    int yq0 = (y - 1) >> 1;
    float wy = sy - (float)yq0;
    int y0c = min(max(yq0, 0), HIN - 1);
    int y1c = min(max(yq0 + 1, 0), HIN - 1);
    const int xo = tid & 63;
    const int cj = tid >> 6;
    float sx = 0.5f * xo - 0.25f;
    int xq0 = (xo - 1) >> 1;
    float wx = sx - (float)xq0;
    int x0c = min(max(xq0, 0), WIN_ - 1);
    int x1c = min(max(xq0 + 1, 0), WIN_ - 1);
    for (int cc = 0; cc < 4; cc++) {
        __syncthreads();
        #pragma unroll
        for (int i = 0; i < 4; i++) {
            int idx = tid * 4 + i;
            int c = idx >> 4;
            int rowh = (idx >> 3) & 1;
            int part = idx & 7;
            int ysrc = rowh ? y1c : y0c;
            float4 v = *reinterpret_cast<const float4*>(
                x + ((size_t)(b * CIN + cc * 64 + c) * HIN + ysrc) * WIN_ + part * 4);
            *reinterpret_cast<float4*>(sf + ((c * 2 + rowh) * 32 + part * 4)) = v;
        }
        __syncthreads();
        unsigned short ov[16];
        #pragma unroll
        for (int j = 0; j < 16; j++) {
            int c = cj * 16 + j;
            const float* r0 = sf + (c * 2 + 0) * 32;
            const float* r1 = sf + (c * 2 + 1) * 32;
            float v = (1.f - wy) * ((1.f - wx) * r0[x0c] + wx * r0[x1c])
                    +        wy  * ((1.f - wx) * r1[x0c] + wx * r1[x1c]);
            ov[j] = f2bf(v);
        }
        unsigned short* dst = Xt + ((size_t)((b * 16 + y) * 64 + xo)) * 256 + cc * 64 + cj * 16;
        *reinterpret_cast<u16x8*>(dst)     = *reinterpret_cast<u16x8*>(ov);
        *reinterpret_cast<u16x8*>(dst + 8) = *reinterpret_cast<u16x8*>(ov + 8);
    }
}

// ---------------- weight transform: Wt[s][co][ci] bf16 ----------------
__global__ void k_wt(const float* __restrict__ conv_w, unsigned short* __restrict__ Wt) {
    int e = blockIdx.x * 256 + threadIdx.x;
    int ci = e & 255;
    int co = (e >> 8) & 255;
    int s  = e >> 16;
    Wt[(size_t)(s * 256 + co) * 256 + ci] = f2bf(conv_w[(size_t)(co * 256 + ci) * 9 + s]);
}

// ---------------- conv3x3 MFMA implicit GEMM + fused bias/ReLU/pool → enc_bf ----------------
__global__ void __launch_bounds__(256) k_convmm(const unsigned short* __restrict__ Xt,
        const unsigned short* __restrict__ Wt, const float* __restrict__ conv_b,
        unsigned short* __restrict__ enc_bf) {
    __shared__ __align__(16) char smem[34048];
    unsigned short* A_s = (unsigned short*)smem;
    unsigned short* B_s = A_s + 128 * 40;
    float* pool = (float*)smem;
    const int mt = blockIdx.x;
    const int n0 = blockIdx.y * 128;
    const int b = mt >> 3;
    const int y0 = (mt & 7) * 2;
    const int tid = threadIdx.x;
    const int wave = tid >> 6, lane = tid & 63;
    const int mq = (wave & 1) * 64, nq = (wave >> 1) * 64;
    const int lm = lane & 15, lq = lane >> 4;
    f32x4 acc[4][4];
    #pragma unroll
    for (int mi = 0; mi < 4; mi++)
        #pragma unroll
        for (int ni = 0; ni < 4; ni++)
            #pragma unroll
            for (int r = 0; r < 4; r++) acc[mi][ni][r] = 0.f;

    for (int s9 = 0; s9 < 9; s9++) {
        const int ky = s9 / 3, kx = s9 % 3;
        const unsigned short* Wb = Wt + (size_t)s9 * 256 * 256;
        for (int kc = 0; kc < 256; kc += 32) {
            __syncthreads();
            #pragma unroll
            for (int it = 0; it < 2; it++) {
                int s2 = tid + it * 256;
                int pix = s2 >> 2, q4 = s2 & 3;
                int yy = y0 + (pix >> 6) + ky - 1;
                int xx = (pix & 63) + kx - 1;
                u16x8 va = {0, 0, 0, 0, 0, 0, 0, 0};
                if ((unsigned)yy < 16u && (unsigned)xx < 64u)
                    va = *reinterpret_cast<const u16x8*>(
                        Xt + ((size_t)((b * 16 + yy) * 64 + xx)) * 256 + kc + q4 * 8);
                *reinterpret_cast<u16x8*>(A_s + pix * 40 + q4 * 8) = va;
                u16x8 vb = *reinterpret_cast<const u16x8*>(
                    Wb + (size_t)(n0 + pix) * 256 + kc + q4 * 8);
                *reinterpret_cast<u16x8*>(B_s + pix * 40 + q4 * 8) = vb;
            }
            __syncthreads();
            short8 af[4], bfr[4];
            #pragma unroll
            for (int mi = 0; mi < 4; mi++)
                af[mi] = *reinterpret_cast<const short8*>(A_s + (mq + mi * 16 + lm) * 40 + lq * 8);
            #pragma unroll
            for (int ni = 0; ni < 4; ni++)
                bfr[ni] = *reinterpret_cast<const short8*>(B_s + (nq + ni * 16 + lm) * 40 + lq * 8);
            #pragma unroll
            for (int mi = 0; mi < 4; mi++)
                #pragma unroll
                for (int ni = 0; ni < 4; ni++)
                    acc[mi][ni] = __builtin_amdgcn_mfma_f32_16x16x32_bf16(
                        af[mi], bfr[ni], acc[mi][ni], 0, 0, 0);
        }
    }
    __syncthreads();
    #pragma unroll
    for (int mi = 0; mi < 4; mi++) {
        int px0 = mi * 8 + lq * 2;
        #pragma unroll
        for (int ni = 0; ni < 4; ni++) {
            int nl = nq + ni * 16 + lm;
            float pa = fmaxf(acc[mi][ni][0], acc[mi][ni][1]);
            float pb = fmaxf(acc[mi][ni][2], acc[mi][ni][3]);
            pool[((wave & 1) * 32 + px0) * 132 + nl] = pa;
            pool[((wave & 1) * 32 + px0 + 1) * 132 + nl] = pb;
        }
    }
    __syncthreads();
    {
        int base = tid * 16;
        int px = base >> 7;
        int nb = base & 127;
        unsigned short ov[16];
        #pragma unroll
        for (int i = 0; i < 16; i++) {
            int n = nb + i;
            float v = fmaxf(pool[px * 132 + n], pool[(32 + px) * 132 + n]) + conv_b[n0 + n];
            ov[i] = f2bf(fmaxf(v, 0.f));
        }
        unsigned short* dst = enc_bf + ((size_t)b * L + (mt & 7) * 32 + px) * CENC + n0 + nb;
        *reinterpret_cast<u16x8*>(dst)     = *reinterpret_cast<u16x8*>(ov);
        *reinterpret_cast<u16x8*>(dst + 8) = *reinterpret_cast<u16x8*>(ov + 8);
    }
}

// ---------------- positional channels 256..295 (bf16) + pos2t[40][256] bf16 ----------------
__global__ void k_encpos(const float* __restrict__ x_emb, const float* __restrict__ y_emb,
                         unsigned short* __restrict__ enc_bf, unsigned short* __restrict__ pos2t) {
    int b = blockIdx.x, l = threadIdx.x;
    int yl = l >> 5, xl = l & 31;
    unsigned short* e = enc_bf + (size_t)(b * L + l) * CENC + 256;
    #pragma unroll
    for (int c = 0; c < 32; c++) e[c] = f2bf(x_emb[xl * 32 + c]);
    #pragma unroll
    for (int c = 0; c < 8; c++) e[32 + c] = f2bf(y_emb[yl * 8 + c]);
    if (b == 0) {
        #pragma unroll
        for (int c = 0; c < 32; c++) pos2t[c * 256 + l] = f2bf(x_emb[xl * 32 + c]);
        #pragma unroll
        for (int c = 0; c < 8; c++) pos2t[(32 + c) * 256 + l] = f2bf(y_emb[yl * 8 + c]);
    }
}

// ---------------- enc_tf8[b][c][l] fp8 (c<256) ----------------
__global__ void __launch_bounds__(256) k_enctf8(const unsigned short* __restrict__ enc_bf,
                                                unsigned char* __restrict__ enc_tf8) {
    __shared__ unsigned short s[64 * 264];
    const int c0 = blockIdx.x * 64;
    const int b = blockIdx.y;
    const int tid = threadIdx.x;
    #pragma unroll
    for (int j = 0; j < 8; j++) {
        u16x8 u = *reinterpret_cast<const u16x8*>(
            enc_bf + ((size_t)b * L + tid) * CENC + c0 + j * 8);
        #pragma unroll
        for (int k = 0; k < 8; k++) s[(j * 8 + k) * 264 + tid] = u[k];
    }
    __syncthreads();
    {
        int c = tid >> 2, lp = tid & 3;
        const unsigned short* row = s + c * 264 + lp * 64;
        unsigned char* dst = enc_tf8 + ((size_t)b * 256 + c0 + c) * 256 + lp * 64;
        #pragma unroll
        for (int i = 0; i < 8; i++) {
            unsigned char ob[8];
            #pragma unroll
            for (int j = 0; j < 8; j++) ob[j] = f2f8(bf2f(row[i * 8 + j]));
            *reinterpret_cast<uint2*>(dst + i * 8) = *reinterpret_cast<uint2*>(ob);
        }
    }
}

// ---------------- E[v][h] fp32 ----------------
__global__ void __launch_bounds__(256) k_etab(const float* __restrict__ emb_dec,
                                              const float* __restrict__ word_w,
                                              const float* __restrict__ word_b,
                                              float* __restrict__ E) {
    __shared__ float er[NC];
    int row = blockIdx.x, tid = threadIdx.x;
    for (int k = tid; k < NC; k += 256) er[k] = emb_dec[(size_t)row * NC + k];
    __syncthreads();
    float a = word_b[tid];
    for (int k = 0; k < NC; k++) a += er[k] * word_w[(size_t)tid * NC + k];
    E[(size_t)row * HID + tid] = a;
}

// ---------------- fp8 weight casts: wA_f8[256][256], ow_f8[163][256] ----------------
__global__ void k_prep(const float* __restrict__ attn_w, const float* __restrict__ out_w,
                       unsigned char* __restrict__ wA_f8, unsigned char* __restrict__ ow_f8) {
    int o = blockIdx.x, k = threadIdx.x;
    wA_f8[(size_t)o * 256 + k] = f2f8(attn_w[(size_t)o * 552 + k]);
    if (o < NC) ow_f8[(size_t)o * 256 + k] = f2f8(out_w[(size_t)o * 256 + k]);
}

// ---------------- GRU weights fp8, k-major: Wg1T[k<320][g], Wg2T[k<256][g] ----------------
__global__ void __launch_bounds__(768) k_wg(const float* __restrict__ wih,
                                            const float* __restrict__ whh,
                                            unsigned char* __restrict__ Wg1T,
                                            unsigned char* __restrict__ Wg2T) {
    int kidx = blockIdx.x, g = threadIdx.x;
    if (kidx < 320) {
        float v = (kidx < 296) ? wih[(size_t)g * 552 + 256 + kidx] : 0.f;
        Wg1T[(size_t)kidx * 768 + g] = f2f8(v);
    } else {
        int k2 = kidx - 320;
        Wg2T[(size_t)k2 * 768 + g] = f2f8(whh[(size_t)g * 256 + k2]);
    }
}
__global__ void __launch_bounds__(768) k_wge(const float* __restrict__ wih,
                                             unsigned short* __restrict__ WgE) {
    int k = blockIdx.x, g = threadIdx.x;
    WgE[(size_t)k * 768 + g] = f2bf(wih[(size_t)g * 552 + k]);
}
// giE[v][g] = emb-part of gi + bih
__global__ void __launch_bounds__(768) k_gie(const float* __restrict__ E,
                                             const unsigned short* __restrict__ WgE,
                                             const float* __restrict__ bih,
                                             float* __restrict__ giE) {
    __shared__ float er[256];
    int v = blockIdx.x, g = threadIdx.x;
    if (g < 256) er[g] = E[(size_t)v * 256 + g];
    __syncthreads();
    float a = bih[g];
    #pragma unroll 4
    for (int k = 0; k < 256; k++) a += er[k] * bf2f(WgE[(size_t)k * 768 + g]);
    giE[(size_t)v * 768 + g] = a;
}

// ---------------- ep8[b][l][h] fp8 ----------------
__global__ void __launch_bounds__(256) k_ep(const unsigned short* __restrict__ enc_bf,
                                            const float* __restrict__ attn_w,
                                            unsigned char* __restrict__ ep8) {
    __shared__ __align__(16) float eS[16][132];
    __shared__ __align__(16) float wS[16][36];
    const int l0 = blockIdx.x * 128;
    const int h0 = blockIdx.y * 32;
    const int b = blockIdx.z;
    const int tid = threadIdx.x;
    const int hh = tid >> 5, ll = tid & 31;
    float acc[4][4];
    #pragma unroll
    for (int s2 = 0; s2 < 4; s2++)
        #pragma unroll
        for (int r = 0; r < 4; r++) acc[s2][r] = 0.f;
    for (int kc = 0; kc < CENC; kc += 16) {
        const int kn = min(16, CENC - kc);
        __syncthreads();
        #pragma unroll
        for (int it = 0; it < 2; it++) {
            int idx = it * 256 + tid;
            int lq = idx >> 2, kq = idx & 3;
            float v0 = 0.f, v1 = 0.f, v2 = 0.f, v3 = 0.f;
            if (kq * 4 < kn) {
                ushort4 u = *reinterpret_cast<const ushort4*>(
                    enc_bf + (size_t)(b * L + l0 + lq) * CENC + kc + kq * 4);
                v0 = bf2f(u.x); v1 = bf2f(u.y); v2 = bf2f(u.z); v3 = bf2f(u.w);
            }
            eS[kq * 4 + 0][lq] = v0; eS[kq * 4 + 1][lq] = v1;
            eS[kq * 4 + 2][lq] = v2; eS[kq * 4 + 3][lq] = v3;
        }
        if (tid < 128) {
            int hq = tid >> 2, kq = tid & 3;
            float4 v = make_float4(0.f, 0.f, 0.f, 0.f);
            if (kq * 4 < kn)
                v = *reinterpret_cast<const float4*>(attn_w + (size_t)(h0 + hq) * 552 + 256 + kc + kq * 4);
            wS[kq * 4 + 0][hq] = v.x; wS[kq * 4 + 1][hq] = v.y;
            wS[kq * 4 + 2][hq] = v.z; wS[kq * 4 + 3][hq] = v.w;
        }
        __syncthreads();
        #pragma unroll
        for (int k = 0; k < 16; k++) {
            float4 e = *reinterpret_cast<const float4*>(&eS[k][ll * 4]);
            float4 w = *reinterpret_cast<const float4*>(&wS[k][hh * 4]);
            float ev[4] = {e.x, e.y, e.z, e.w};
            float wv[4] = {w.x, w.y, w.z, w.w};
            #pragma unroll
            for (int s2 = 0; s2 < 4; s2++)
                #pragma unroll
                for (int r = 0; r < 4; r++) acc[s2][r] += wv[s2] * ev[r];
        }
    }
    #pragma unroll
    for (int r = 0; r < 4; r++) {
        uchar4 o;
        o.x = f2f8(acc[0][r]); o.y = f2f8(acc[1][r]);
        o.z = f2f8(acc[2][r]); o.w = f2f8(acc[3][r]);
        *reinterpret_cast<uchar4*>(
            ep8 + ((size_t)(b * L) + l0 + ll * 4 + r) * 256 + h0 + hh * 4) = o;
    }
}

// ---------------- fully-independent per-b recurrence; ep mostly LDS-resident ----------------
__global__ void __launch_bounds__(1024) k_loop4(
        const unsigned char* __restrict__ ep8, const unsigned char* __restrict__ enc_tf8,
        const unsigned char* __restrict__ wA_f8, const unsigned char* __restrict__ ow_f8,
        const unsigned char* __restrict__ Wg1T, const unsigned char* __restrict__ Wg2T,
        const float* __restrict__ giE, const unsigned short* __restrict__ pos2t,
        const float* __restrict__ attn_b, const float* __restrict__ attn_v,
        const float* __restrict__ out_b, const float* __restrict__ bhh,
        const int* __restrict__ dec_tgt, const int* __restrict__ word_tgt,
        float* __restrict__ nllG) {
    const int b = blockIdx.x;
    const int tid = threadIdx.x;
    const int wave = tid >> 6, lane = tid & 63;
    const int q = lane >> 4, j16 = lane & 15;

    __shared__ __align__(16) unsigned char ep_lds[EPL * 256];  // 38.9KB
    __shared__ float parts[4][768];                            // 12KB
    __shared__ float gi_s[768], gh_s[768];
    __shared__ float hS_f[256];
    __shared__ float scr[256];
    __shared__ float ctx_s[320];
    __shared__ unsigned short hS_bf[256], hp_bf[256], v_bf[256], s_bf[256];
    __shared__ float red[16];
    __shared__ float nllA[1];

    if (tid < 256) v_bf[tid] = f2bf(attn_v[tid]);
    if (tid >= 296 && tid < 320) ctx_s[tid] = 0.f;   // K-pad, never rewritten
    if (tid == 0) nllA[0] = 0.f;
    // preload ep rows [0, EPL) into LDS (16B per slot)
    for (int i = tid; i < EPL * 16; i += 1024) {
        *reinterpret_cast<uint4*>(ep_lds + i * 16) =
            *reinterpret_cast<const uint4*>(ep8 + (size_t)b * L * 256 + i * 16);
    }
    __syncthreads();

    for (int t = 0; t <= T; t++) {
        __syncthreads();
        // ---- s0: GRU pointwise h_t from gi_s/gh_s of step t-1 ----
        if (tid < 256) {
            float h;
            if (t == 0) {
                h = 0.f;
            } else {
                float hold = hS_f[tid];
                int tokp = (t == 1) ? 0 : dec_tgt[b * T + (t - 2)];
                const float* gE = giE + (size_t)tokp * 768;
                float r_ = fast_sigm(gi_s[tid] + gE[tid] + gh_s[tid] + bhh[tid]);
                float z_ = fast_sigm(gi_s[256 + tid] + gE[256 + tid] + gh_s[256 + tid] + bhh[256 + tid]);
                float n_ = fast_tanh(gi_s[512 + tid] + gE[512 + tid] + r_ * (gh_s[512 + tid] + bhh[512 + tid]));
                h = (1.f - z_) * n_ + z_ * hold;
            }
            hS_f[tid] = h;
            hS_bf[tid] = f2bf(h);
        }
        __syncthreads();

        // ---- s1 (t>0): logits(h_t) + nll; quarter-wave rows (16 lanes x 16B) ----
        if (t > 0) {
            #pragma unroll
            for (int it = 0; it < 3; it++) {
                int row = it * 64 + wave * 4 + q;
                float d = 0.f;
                if (row < NC) {
                    uint4 w8 = *reinterpret_cast<const uint4*>(ow_f8 + (size_t)row * 256 + j16 * 16);
                    d = dot16_f8_bf(w8, hS_bf + j16 * 16);
                }
                d = q16_red_sum(d);
                if (j16 == 0 && row < NC) scr[row] = d + out_b[row];
            }
            __syncthreads();
            float lg = -1e30f;
            if (tid < 256) {
                if (tid < NC) lg = scr[tid];
                float m = wave_red_max(lg);
                if ((tid & 63) == 0) red[tid >> 6] = m;
            }
            __syncthreads();
            float M = fmaxf(fmaxf(red[0], red[1]), fmaxf(red[2], red[3]));
            if (tid < 256) {
                float e = (tid < NC) ? __expf(lg - M) : 0.f;
                float sm = wave_red_sum(e);
                if ((tid & 63) == 0) red[8 + (tid >> 6)] = sm;
            }
            __syncthreads();
            if (tid == 0) {
                float S = red[8] + red[9] + red[10] + red[11];
                int tgt = word_tgt[b * T + (t - 1)];
                if (tgt >= 0) nllA[0] += M + __logf(S) - scr[tgt];
            }
            __syncthreads();
        }
        if (t == T) break;

        // ---- s2: hp = h @ Wh^T + attn_b ----
        #pragma unroll
        for (int it = 0; it < 4; it++) {
            int row = it * 64 + wave * 4 + q;
            uint4 w8 = *reinterpret_cast<const uint4*>(wA_f8 + (size_t)row * 256 + j16 * 16);
            float d = dot16_f8_bf(w8, hS_bf + j16 * 16);
            d = q16_red_sum(d);
            if (j16 == 0) hp_bf[row] = f2bf(d + attn_b[row]);
        }
        __syncthreads();

        // ---- s3: scores over l (ep rows: LDS for row<EPL, global tail otherwise) ----
        #pragma unroll
        for (int it = 0; it < 4; it++) {
            int row = it * 64 + wave * 4 + q;
            uint4 e8;
            if (row < EPL)
                e8 = *reinterpret_cast<const uint4*>(ep_lds + row * 256 + j16 * 16);
            else
                e8 = *reinterpret_cast<const uint4*>(ep8 + ((size_t)b * L + row) * 256 + j16 * 16);
            u16x8 hp0 = *reinterpret_cast<const u16x8*>(hp_bf + j16 * 16);
            u16x8 hp1 = *reinterpret_cast<const u16x8*>(hp_bf + j16 * 16 + 8);
            u16x8 vv0 = *reinterpret_cast<const u16x8*>(v_bf + j16 * 16);
            u16x8 vv1 = *reinterpret_cast<const u16x8*>(v_bf + j16 * 16 + 8);
            float4 fa = f8x4(e8.x), fb = f8x4(e8.y), fc = f8x4(e8.z), fd = f8x4(e8.w);
            float ev[16] = {fa.x, fa.y, fa.z, fa.w, fb.x, fb.y, fb.z, fb.w,
                            fc.x, fc.y, fc.z, fc.w, fd.x, fd.y, fd.z, fd.w};
            float d = 0.f;
            #pragma unroll
            for (int j = 0; j < 8; j++)
                d += bf2f(vv0[j]) * fast_tanh(ev[j] + bf2f(hp0[j]));
            #pragma unroll
            for (int j = 0; j < 8; j++)
                d += bf2f(vv1[j]) * fast_tanh(ev[8 + j] + bf2f(hp1[j]));
            d = q16_red_sum(d);
            if (j16 == 0) scr[row] = d;
        }
        __syncthreads();
        float sc = -1e30f;
        if (tid < 256) {
            sc = scr[tid];
            float m = wave_red_max(sc);
            if ((tid & 63) == 0) red[tid >> 6] = m;
        }
        __syncthreads();
        float M2 = fmaxf(fmaxf(red[0], red[1]), fmaxf(red[2], red[3]));
        if (tid < 256) {
            float e2 = __expf(sc - M2);
            s_bf[tid] = f2bf(e2);
            float sm = wave_red_sum(e2);
            if ((tid & 63) == 0) red[8 + (tid >> 6)] = sm;
        }
        __syncthreads();
        float invS = __builtin_amdgcn_rcpf(red[8] + red[9] + red[10] + red[11]);

        // ---- s4: ctx (fp8 enc rows) + positional rows → ctx_s[0..295] ----
        #pragma unroll
        for (int it = 0; it < 4; it++) {
            int row = it * 64 + wave * 4 + q;
            uint4 e8 = *reinterpret_cast<const uint4*>(
                enc_tf8 + ((size_t)b * 256 + row) * 256 + j16 * 16);
            float d = dot16_f8_bf(e8, s_bf + j16 * 16);
            d = q16_red_sum(d);
            if (j16 == 0) ctx_s[row] = d * invS;
        }
        {   // positional rows 256..295
            int row = 256 + wave * 4 + q;
            float d = 0.f;
            if (row < 296) {
                u16x8 p0 = *reinterpret_cast<const u16x8*>(pos2t + (size_t)(row - 256) * 256 + j16 * 16);
                u16x8 p1 = *reinterpret_cast<const u16x8*>(pos2t + (size_t)(row - 256) * 256 + j16 * 16 + 8);
                u16x8 s0 = *reinterpret_cast<const u16x8*>(s_bf + j16 * 16);
                u16x8 s1 = *reinterpret_cast<const u16x8*>(s_bf + j16 * 16 + 8);
                #pragma unroll
                for (int j = 0; j < 8; j++) d += bf2f(p0[j]) * bf2f(s0[j]);
                #pragma unroll
                for (int j = 0; j < 8; j++) d += bf2f(p1[j]) * bf2f(s1[j]);
            }
            d = q16_red_sum(d);
            if (j16 == 0 && row < 296) ctx_s[row] = d * invS;
        }
        __syncthreads();

        // ---- s5a: gi_ctx = Wg1T^T · ctx (fp8, column-per-thread, 4 K-slices of 80) ----
        if (tid < 768) {
            int ks = tid / 192, g0 = (tid % 192) * 4;
            float a0 = 0.f, a1 = 0.f, a2 = 0.f, a3 = 0.f;
            #pragma unroll 8
            for (int kk = 0; kk < 80; kk++) {
                int k = ks * 80 + kk;
                float c = ctx_s[k];
                unsigned int w = *reinterpret_cast<const unsigned int*>(Wg1T + (size_t)k * 768 + g0);
                float4 f = f8x4(w);
                a0 = fmaf(c, f.x, a0); a1 = fmaf(c, f.y, a1);
                a2 = fmaf(c, f.z, a2); a3 = fmaf(c, f.w, a3);
            }
            *reinterpret_cast<float4*>(&parts[ks][g0]) = make_float4(a0, a1, a2, a3);
        }
        __syncthreads();
        if (tid < 768) gi_s[tid] = parts[0][tid] + parts[1][tid] + parts[2][tid] + parts[3][tid];
        __syncthreads();
        // ---- s5b: gh = Wg2T^T · h (4 K-slices of 64) ----
        if (tid < 768) {
            int ks = tid / 192, g0 = (tid % 192) * 4;
            float a0 = 0.f, a1 = 0.f, a2 = 0.f, a3 = 0.f;
            #pragma unroll 8
            for (int kk = 0; kk < 64; kk++) {
                int k = ks * 64 + kk;
                float hv = hS_f[k];
                unsigned int w = *reinterpret_cast<const unsigned int*>(Wg2T + (size_t)k * 768 + g0);
                float4 f = f8x4(w);
                a0 = fmaf(hv, f.x, a0); a1 = fmaf(hv, f.y, a1);
                a2 = fmaf(hv, f.z, a2); a3 = fmaf(hv, f.w, a3);
            }
            *reinterpret_cast<float4*>(&parts[ks][g0]) = make_float4(a0, a1, a2, a3);
        }
        __syncthreads();
        if (tid < 768) gh_s[tid] = parts[0][tid] + parts[1][tid] + parts[2][tid] + parts[3][tid];
    }

    if (tid == 0) nllG[b] = nllA[0];
}

// ---------------- loss = 0.2 * mean_b(nll) ----------------
__global__ void k_reduce(const float* __restrict__ nll, float* __restrict__ out) {
    __shared__ float red[2];
    float v = nll[threadIdx.x];
    v = wave_red_sum(v);
    if ((threadIdx.x & 63) == 0) red[threadIdx.x >> 6] = v;
    __syncthreads();
    if (threadIdx.x == 0) out[0] = 0.2f * (red[0] + red[1]) * (1.f / 128.f);
}

extern "C" void kernel_launch(void* const* d_in, const int* in_sizes, int n_in,
                              void* d_out, int out_size, void* d_ws, size_t ws_size,
                              hipStream_t stream) {
    const float* x        = (const float*)d_in[0];
    const int*   dec_tgt  = (const int*)d_in[1];
    const int*   word_tgt = (const int*)d_in[2];
    const float* conv_w   = (const float*)d_in[3];
    const float* conv_b   = (const float*)d_in[4];
    const float* emb_dec  = (const float*)d_in[5];
    const float* word_w   = (const float*)d_in[6];
    const float* word_b   = (const float*)d_in[7];
    const float* attn_w   = (const float*)d_in[8];
    const float* attn_b   = (const float*)d_in[9];
    const float* attn_v   = (const float*)d_in[10];
    const float* gru_wih  = (const float*)d_in[11];
    const float* gru_bih  = (const float*)d_in[12];
    const float* gru_whh  = (const float*)d_in[13];
    const float* gru_bhh  = (const float*)d_in[14];
    const float* out_w    = (const float*)d_in[15];
    const float* out_b    = (const float*)d_in[16];
    const float* x_emb    = (const float*)d_in[17];
    const float* y_emb    = (const float*)d_in[18];

    char* ws = (char*)d_ws;
    size_t off = 0;
    auto alloc = [&](size_t bytes) -> void* {
        void* p = ws + off;
        off = (off + bytes + 255) & ~(size_t)255;
        return p;
    };
    unsigned short* Xt     = (unsigned short*)alloc((size_t)B * 16 * 64 * 256 * 2);   // 64MiB
    unsigned short* enc_bf = (unsigned short*)alloc((size_t)B * L * CENC * 2 + 64);
    unsigned short* Wt     = (unsigned short*)alloc((size_t)9 * 256 * 256 * 2);
    float* E      = (float*)alloc((size_t)NC * HID * 4);
    unsigned char* wA_f8   = (unsigned char*)alloc((size_t)HID * HID);
    unsigned char* ow_f8   = (unsigned char*)alloc((size_t)NC * HID);
    unsigned char* Wg1T    = (unsigned char*)alloc((size_t)320 * 768);
    unsigned char* Wg2T    = (unsigned char*)alloc((size_t)256 * 768);
    unsigned short* WgE    = (unsigned short*)alloc((size_t)256 * 768 * 2);
    float* giE    = (float*)alloc((size_t)NC * 768 * 4);
    unsigned char* enc_tf8 = (unsigned char*)alloc((size_t)B * 256 * 256);            // 8.4MB
    unsigned short* pos2t  = (unsigned short*)alloc((size_t)40 * 256 * 2);
    float* nllG   = (float*)alloc((size_t)B * 4);
    // ep8 (8.4MB) aliases Xt (dead after k_convmm)
    unsigned char* ep8 = (unsigned char*)Xt;
    float* out    = (float*)d_out;

    hipLaunchKernelGGL(k_upsxt, dim3(16, 128), dim3(256), 0, stream, x, Xt);
    hipLaunchKernelGGL(k_wt, dim3(2304), dim3(256), 0, stream, conv_w, Wt);
    hipLaunchKernelGGL(k_encpos, dim3(128), dim3(256), 0, stream, x_emb, y_emb, enc_bf, pos2t);
    hipLaunchKernelGGL(k_convmm, dim3(1024, 2), dim3(256), 0, stream, Xt, Wt, conv_b, enc_bf);
    hipLaunchKernelGGL(k_etab, dim3(163), dim3(256), 0, stream, emb_dec, word_w, word_b, E);
    hipLaunchKernelGGL(k_prep, dim3(256), dim3(256), 0, stream, attn_w, out_w, wA_f8, ow_f8);
    hipLaunchKernelGGL(k_wg, dim3(576), dim3(768), 0, stream, gru_wih, gru_whh, Wg1T, Wg2T);
    hipLaunchKernelGGL(k_wge, dim3(256), dim3(768), 0, stream, gru_wih, WgE);
    hipLaunchKernelGGL(k_gie, dim3(163), dim3(768), 0, stream, E, WgE, gru_bih, giE);
    hipLaunchKernelGGL(k_ep, dim3(2, 8, 128), dim3(256), 0, stream, enc_bf, attn_w, ep8);
    hipLaunchKernelGGL(k_enctf8, dim3(4, 128), dim3(256), 0, stream, enc_bf, enc_tf8);
    hipLaunchKernelGGL(k_loop4, dim3(128), dim3(1024), 0, stream,
                       ep8, enc_tf8, wA_f8, ow_f8, Wg1T, Wg2T, giE, pos2t,
                       attn_b, attn_v, out_b, gru_bhh, dec_tgt, word_tgt, nllG);
    hipLaunchKernelGGL(k_reduce, dim3(1), dim3(128), 0, stream, nllG, out);
}